// Round 7
// baseline (34.618 us; speedup 1.0000x reference)
//
#include <hip/hip_runtime.h>
#include <math.h>

#define KOSC 64
#define CHUNK 8
#define NSPLIT 8                   // waves per block / oscillator split factor
#define QH 2                       // quads per thread per bank (2*4 = 8 osc)
#define TWO_PI_F  6.28318530717958647692f
#define INV2PI_F  0.15915494309189533577f
#define MIN_SLOPE -2.0f
#define MAX_SLOPE  8.0f

// ---------------------------------------------------------------------------
// Wave-wide (64-lane) reductions for the softmax in the precompute kernel.
// ---------------------------------------------------------------------------
__device__ __forceinline__ float wave_reduce_max(float v) {
#pragma unroll
    for (int off = 32; off > 0; off >>= 1)
        v = fmaxf(v, __shfl_xor(v, off, 64));
    return v;
}
__device__ __forceinline__ float wave_reduce_sum(float v) {
#pragma unroll
    for (int off = 32; off > 0; off >>= 1)
        v += __shfl_xor(v, off, 64);
    return v;
}

// ---------------------------------------------------------------------------
// Precompute per-oscillator constants. 128 threads = 2 waves:
//   wave 0 -> modulator bank, wave 1 -> carrier bank.
// banks[k*8 + c]: c = {f, cd, sd, 2cd, s, s*off + 3.5*s*dtn, w, 0}
//   (dtn = dt/tmax; slot 5 is the frozen-midpoint envelope-arg constant)
// scalars = { sig(rev), 1/tmax, dt }
// ---------------------------------------------------------------------------
__global__ void precompute_kernel(
    const float* __restrict__ t, int T,
    const float* __restrict__ cfq, const float* __restrict__ cwt,
    const float* __restrict__ mfq, const float* __restrict__ mwt,
    const float* __restrict__ po,
    const float* __restrict__ ces, const float* __restrict__ ceo,
    const float* __restrict__ mes, const float* __restrict__ meo,
    float* __restrict__ banks, float* __restrict__ scalars)
{
    const int k    = threadIdx.x;     // 0..127
    const int bank = k >> 6;          // 0 = modulator, 1 = carrier
    const int idx  = k & 63;

    const float fq = bank ? cfq[idx] : mfq[idx];
    const float wt = bank ? cwt[idx] : mwt[idx];
    const float sl = bank ? ces[idx] : mes[idx];
    const float of = bank ? ceo[idx] : meo[idx];

    // per-wave softmax over the 64 weights of this bank
    const float mx = wave_reduce_max(wt);
    const float ex = expf(wt - mx);
    const float sm = wave_reduce_sum(ex);
    const float w  = ex / sm;

    // envelope constants
    const float sg   = 1.0f / (1.0f + expf(-sl));
    const float s    = exp2f(sg * (MAX_SLOPE - MIN_SLOPE) + MIN_SLOPE);
    const float offv = tanhf(of) * 0.5f;

    const float dt   = t[1] - t[0];           // t[0]==0 -> exact
    const float tmax = t[T - 1];
    const float dtn  = dt / tmax;

    // rotation constants in f64 (one-time cost)
    const double th = (double)TWO_PI_F * (double)fq * (double)dt;
    const float cd  = (float)cos(th);
    const float sd  = (float)sin(th);

    float* B = banks + k * 8;
    B[0] = fq;
    B[1] = cd;
    B[2] = sd;
    B[3] = cd + cd;                            // Chebyshev coefficient 2cos(th)
    B[4] = s;
    B[5] = fmaf(s * dtn, 0.5f * (float)(CHUNK - 1), s * offv);  // mid-chunk arg const
    B[6] = w;
    B[7] = 0.0f;

    if (k == 0) {
        scalars[0] = 1.0f / (1.0f + expf(-po[0]));  // phase offset, REVOLUTIONS
        scalars[1] = 1.0f / tmax;
        scalars[2] = dt;
    }
}

// ---------------------------------------------------------------------------
// Chebyshev oscillator state: cos/sin sequences advanced with the 3-term
// recurrence x_{j+1} = 2cos(th)*x_j - x_{j-1}  (1 fma per step per sequence;
// c2 stays in SGPR). The weighted envelope is FROZEN at the chunk midpoint
// (error <= |b'|*da/2 ~ 4e-4 weighted).
// ---------------------------------------------------------------------------
struct Cheb {
    float c2;              // 2cos(theta) (wave-uniform -> SGPR)
    float xc0, xc1;        // cos sequence: x_j, x_{j+1}
    float xs0, xs1;        // sin sequence
    float wb, wbf;         // frozen weighted bell, and f * wb
};

__device__ __forceinline__ void osc_setup(const float* __restrict__ b,
                                          float t0, float tn0, float sig,
                                          Cheb& o)
{
    const float f  = b[0];
    const float cd = b[1];
    const float sd = b[2];
    o.c2           = b[3];

    // exact phase at chunk start (Dekker product + Sterbenz frac), revolutions
    const float hi  = f * t0;
    const float lo  = fmaf(f, t0, -hi);
    const float rev = (hi - floorf(hi)) + lo + sig;
    o.xc0 = __builtin_amdgcn_cosf(rev);            // cos(2*pi*rev)
    o.xs0 = __builtin_amdgcn_sinf(rev);

    // second point: rotate once by theta
    o.xc1 = fmaf(-o.xs0, sd, o.xc0 * cd);
    o.xs1 = fmaf( o.xs0, cd, o.xc0 * sd);

    // frozen mid-chunk weighted envelope
    const float a    = fmaf(b[4], tn0, b[5]);
    const float bell = __builtin_amdgcn_rsqf(fmaf(a, a, 1.0f));
    o.wb  = bell * b[6];
    o.wbf = o.wb * f;
}

#define CHEB_ADV(o)                                                   \
    {                                                                 \
        const float nxc = fmaf(o.c2, o.xc1, -o.xc0);                  \
        o.xc0 = o.xc1; o.xc1 = nxc;                                   \
        const float nxs = fmaf(o.c2, o.xs1, -o.xs0);                  \
        o.xs0 = o.xs1; o.xs1 = nxs;                                   \
    }

// ---------------------------------------------------------------------------
// Main kernel: each block = 8 waves covering 64 chunks of 8 samples (512
// samples). The 8 waves split the 64 oscillators of each bank 8-ways (8 osc
// per thread) with WAVE-UNIFORM bank pointers (s_load path). Cross-wave
// combines use owner-thread mapping: thread tau owns sample (c=tau>>3,
// j=tau&7); it sums the 8 partials and (for the modulator) computes ONE
// cos/sin pair per sample, shared back through LDS -> 4x less transcendental
// work than per-wave recompute, and the final store is fully coalesced.
//
// Carrier FM factorization: sum_k wb sin(A_k + m) = cm*S + sm*C;
// first-order time-jitter correction via Sf = sum f*wb*sinA, Cf = sum f*wb*cosA:
//   out_j = cm*S + sm*C + d2p_j*(cm*Cf - sm*Sf).
// ---------------------------------------------------------------------------
__global__ void __launch_bounds__(512, 4) fm_main_kernel(
    const float* __restrict__ t,
    const float* __restrict__ banks,
    const float* __restrict__ scalars,
    float* __restrict__ out, int T)
{
    const int tid = threadIdx.x;
    const int c   = tid & 63;                                   // chunk lane
    const int p   = __builtin_amdgcn_readfirstlane(tid >> 6);   // wave id 0..7
    const int i0  = (blockIdx.x * 64 + c) * CHUNK;              // sample base

    __shared__ float  pbuf[NSPLIT][64][CHUNK + 1];   // partials (mod, then carrier)
    __shared__ float2 tbuf[64][CHUNK + 1];           // cm/sm per (chunk, sample)

    const float sig     = scalars[0];
    const float invtmax = scalars[1];
    const float dt      = scalars[2];

    const float4 ta = *reinterpret_cast<const float4*>(t + i0);
    const float4 tb = *reinterpret_cast<const float4*>(t + i0 + 4);
    const float tj[CHUNK] = {ta.x, ta.y, ta.z, ta.w, tb.x, tb.y, tb.z, tb.w};
    const float t0 = tj[0];

    // 2*pi * (t_j - (t0 + j*dt)): f32 rounding jitter of t, radians per Hz
    float d2p[CHUNK];
    d2p[0] = 0.0f;
#pragma unroll
    for (int j = 1; j < CHUNK; ++j)
        d2p[j] = TWO_PI_F * fmaf(-(float)j, dt, tj[j] - t0);

    const float tn0 = fmaf(t0, invtmax, -0.5f);

    // ---------------- modulator bank (8 osc): Cm = sum wb*cos, Sfm = sum wbf*sin
    float Cm[CHUNK], Sfm[CHUNK];
#pragma unroll
    for (int j = 0; j < CHUNK; ++j) { Cm[j] = 0.0f; Sfm[j] = 0.0f; }

    {
        const float* base = banks + (p * 8) * 8;       // wave-uniform pointer
#pragma unroll 1
        for (int q = 0; q < QH; ++q) {
            const float* B = base + q * 32;            // 4 oscillators per group
            Cheb o0, o1, o2, o3;
            osc_setup(B +  0, t0, tn0, sig, o0);
            osc_setup(B +  8, t0, tn0, sig, o1);
            osc_setup(B + 16, t0, tn0, sig, o2);
            osc_setup(B + 24, t0, tn0, sig, o3);

#pragma unroll
            for (int j = 0; j < CHUNK; ++j) {
#define MOD_STEP(o)                                                   \
                {                                                     \
                    Cm[j]  = fmaf(o.wb,  o.xc0, Cm[j]);               \
                    Sfm[j] = fmaf(o.wbf, o.xs0, Sfm[j]);              \
                }
                MOD_STEP(o0) MOD_STEP(o1) MOD_STEP(o2) MOD_STEP(o3)
#undef MOD_STEP
                if (j < CHUNK - 1) {
                    CHEB_ADV(o0) CHEB_ADV(o1) CHEB_ADV(o2) CHEB_ADV(o3)
                }
            }
        }
    }

    // publish jitter-corrected partial mod
#pragma unroll
    for (int j = 0; j < CHUNK; ++j)
        pbuf[p][c][j] = fmaf(-d2p[j], Sfm[j], Cm[j]);
    __syncthreads();

    // owner-thread combine: thread tau owns sample (cc, jj); one trig pair
    {
        const int cc = tid >> 3;
        const int jj = tid & 7;
        float m = pbuf[0][cc][jj];
#pragma unroll
        for (int w = 1; w < NSPLIT; ++w)
            m += pbuf[w][cc][jj];
        const float mrev = m * INV2PI_F;
        tbuf[cc][jj] = make_float2(__builtin_amdgcn_cosf(mrev),
                                   __builtin_amdgcn_sinf(mrev));
    }
    __syncthreads();

    float cm[CHUNK], sm[CHUNK];
#pragma unroll
    for (int j = 0; j < CHUNK; ++j) {
        const float2 v = tbuf[c][j];
        cm[j] = v.x;
        sm[j] = v.y;
    }

    // ---------------- carrier bank (8 osc): S, C, Sf, Cf sums ---------------
    float S[CHUNK], C[CHUNK], Sf[CHUNK], Cf[CHUNK];
#pragma unroll
    for (int j = 0; j < CHUNK; ++j) { S[j] = 0.0f; C[j] = 0.0f;
                                      Sf[j] = 0.0f; Cf[j] = 0.0f; }

    {
        const float* base = banks + (KOSC + p * 8) * 8;    // wave-uniform
#pragma unroll 1
        for (int q = 0; q < QH; ++q) {
            const float* B = base + q * 32;
            Cheb o0, o1, o2, o3;
            osc_setup(B +  0, t0, tn0, sig, o0);
            osc_setup(B +  8, t0, tn0, sig, o1);
            osc_setup(B + 16, t0, tn0, sig, o2);
            osc_setup(B + 24, t0, tn0, sig, o3);

#pragma unroll
            for (int j = 0; j < CHUNK; ++j) {
#define CAR_STEP(o)                                                   \
                {                                                     \
                    S[j]  = fmaf(o.wb,  o.xs0, S[j]);                 \
                    C[j]  = fmaf(o.wb,  o.xc0, C[j]);                 \
                    Sf[j] = fmaf(o.wbf, o.xs0, Sf[j]);                \
                    Cf[j] = fmaf(o.wbf, o.xc0, Cf[j]);                \
                }
                CAR_STEP(o0) CAR_STEP(o1) CAR_STEP(o2) CAR_STEP(o3)
#undef CAR_STEP
                if (j < CHUNK - 1) {
                    CHEB_ADV(o0) CHEB_ADV(o1) CHEB_ADV(o2) CHEB_ADV(o3)
                }
            }
        }
    }

    // epilogue: FM rotation + jitter correction -> per-wave partial output
    // (overwrites pbuf; safe — all mod-partial reads completed before the
    //  second barrier above)
#pragma unroll
    for (int j = 0; j < CHUNK; ++j) {
        float u = cm[j] * S[j];
        u = fmaf(sm[j], C[j], u);
        float v = cm[j] * Cf[j];
        v = fmaf(-sm[j], Sf[j], v);
        pbuf[p][c][j] = fmaf(d2p[j], v, u);
    }
    __syncthreads();

    // owner-thread final combine; coalesced store (tid == c*8 + j mapping)
    {
        const int cc = tid >> 3;
        const int jj = tid & 7;
        float o = pbuf[0][cc][jj];
#pragma unroll
        for (int w = 1; w < NSPLIT; ++w)
            o += pbuf[w][cc][jj];
        out[blockIdx.x * 512 + tid] = o;
    }
}

// ---------------------------------------------------------------------------
extern "C" void kernel_launch(void* const* d_in, const int* in_sizes, int n_in,
                              void* d_out, int out_size, void* d_ws, size_t ws_size,
                              hipStream_t stream) {
    // setup_inputs() order:
    // 0:t 1:carrier_fq 2:carrier_weight 3:mod_fq 4:mod_weight 5:phase_offset
    // 6:carrier_env_slope 7:carrier_env_offset 8:mod_env_slope 9:mod_env_offset
    const float* t   = (const float*)d_in[0];
    const float* cfq = (const float*)d_in[1];
    const float* cw  = (const float*)d_in[2];
    const float* mfq = (const float*)d_in[3];
    const float* mw  = (const float*)d_in[4];
    const float* po  = (const float*)d_in[5];
    const float* ces = (const float*)d_in[6];
    const float* ceo = (const float*)d_in[7];
    const float* mes = (const float*)d_in[8];
    const float* meo = (const float*)d_in[9];
    const int T = in_sizes[0];

    float* banks   = (float*)d_ws;                       // 128 osc * 8 floats
    float* scalars = banks + 2 * KOSC * 8;               // 3 floats

    precompute_kernel<<<1, 2 * KOSC, 0, stream>>>(t, T, cfq, cw, mfq, mw, po,
                                                  ces, ceo, mes, meo,
                                                  banks, scalars);

    // one block = 8 waves = 64 chunks of 8 samples = 512 samples
    const int grid = T / (CHUNK * 64);        // 2048 blocks for T = 1<<20
    fm_main_kernel<<<grid, 512, 0, stream>>>(t, banks, scalars,
                                             (float*)d_out, T);
}

// Round 8
// 33.331 us; speedup vs baseline: 1.0386x; 1.0386x over previous
//
#include <hip/hip_runtime.h>
#include <math.h>

#define KOSC 64
#define CHUNK 16                   // samples per chunk (per lane)
#define NSPLIT 8                   // waves per block / oscillator split factor
#define QH 2                       // quads per thread per bank (2*4 = 8 osc)
#define TWO_PI_F  6.28318530717958647692f
#define INV2PI_F  0.15915494309189533577f
#define MIN_SLOPE -2.0f
#define MAX_SLOPE  8.0f

// ---------------------------------------------------------------------------
// Wave-wide (64-lane) reductions for the softmax in the precompute kernel.
// ---------------------------------------------------------------------------
__device__ __forceinline__ float wave_reduce_max(float v) {
#pragma unroll
    for (int off = 32; off > 0; off >>= 1)
        v = fmaxf(v, __shfl_xor(v, off, 64));
    return v;
}
__device__ __forceinline__ float wave_reduce_sum(float v) {
#pragma unroll
    for (int off = 32; off > 0; off >>= 1)
        v += __shfl_xor(v, off, 64);
    return v;
}

// ---------------------------------------------------------------------------
// Precompute. 128 threads = 2 waves (wave0 = modulator, wave1 = carrier).
// Each bank's 64 oscillators are SORTED BY FREQUENCY (rank-by-count) so that
// 8 consecutive oscillators form a frequency group with small spread; the
// group mean frequency fbar replaces per-oscillator f in the first-order
// time-jitter correction (residual 2*pi*|f-fbar|*~2e-6 <= ~8e-4 rad).
// banks[slot*8 + c]: c = {f, cd, sd, 2cd, s, s*off, w, 0}   (slot = sorted rank)
// scalars = { sig(rev), 1/tmax, dt, fbar[16] }  (8 mod groups, 8 carrier groups)
// ---------------------------------------------------------------------------
__global__ void precompute_kernel(
    const float* __restrict__ t, int T,
    const float* __restrict__ cfq, const float* __restrict__ cwt,
    const float* __restrict__ mfq, const float* __restrict__ mwt,
    const float* __restrict__ po,
    const float* __restrict__ ces, const float* __restrict__ ceo,
    const float* __restrict__ mes, const float* __restrict__ meo,
    float* __restrict__ banks, float* __restrict__ scalars)
{
    const int k    = threadIdx.x;     // 0..127
    const int bank = k >> 6;          // 0 = modulator, 1 = carrier
    const int idx  = k & 63;

    const float fq = bank ? cfq[idx] : mfq[idx];
    const float wt = bank ? cwt[idx] : mwt[idx];
    const float sl = bank ? ces[idx] : mes[idx];
    const float of = bank ? ceo[idx] : meo[idx];

    // per-wave softmax over the 64 weights of this bank (order-independent)
    const float mx = wave_reduce_max(wt);
    const float ex = expf(wt - mx);
    const float sm = wave_reduce_sum(ex);
    const float w  = ex / sm;

    // envelope constants
    const float sg   = 1.0f / (1.0f + expf(-sl));
    const float s    = exp2f(sg * (MAX_SLOPE - MIN_SLOPE) + MIN_SLOPE);
    const float offv = tanhf(of) * 0.5f;

    const float dt   = t[1] - t[0];           // t[0]==0 -> exact
    const float tmax = t[T - 1];

    // rotation constants in f64 (one-time cost)
    const double th = (double)TWO_PI_F * (double)fq * (double)dt;
    const float cd  = (float)cos(th);
    const float sd  = (float)sin(th);

    // rank of this oscillator within its bank, sorted by frequency ascending
    int rank = 0;
#pragma unroll 1
    for (int j = 0; j < 64; ++j) {
        const float fj = __shfl(fq, j, 64);
        if (fj < fq || (fj == fq && j < idx)) ++rank;
    }

    float* B = banks + (bank * 64 + rank) * 8;
    B[0] = fq;
    B[1] = cd;
    B[2] = sd;
    B[3] = cd + cd;                  // Chebyshev coefficient 2cos(th)
    B[4] = s;
    B[5] = s * offv;
    B[6] = w;
    B[7] = 0.0f;

    if (k == 0) {
        scalars[0] = 1.0f / (1.0f + expf(-po[0]));  // phase offset, REVOLUTIONS
        scalars[1] = 1.0f / tmax;
        scalars[2] = dt;
    }
    __syncthreads();

    // group mean frequencies: 16 groups of 8 sorted oscillators
    if (k < 16) {
        const float* G = banks + (k * 8) * 8;
        float fs = 0.0f;
#pragma unroll
        for (int i = 0; i < 8; ++i) fs += G[i * 8];
        scalars[3 + k] = fs * 0.125f;
    }
}

// ---------------------------------------------------------------------------
// Oscillator chunk state. Trig is initialized at the chunk MIDPOINT sample
// j=7 (exact Dekker split of f*t7 + Sterbenz frac, hw trig in revolutions);
// the Chebyshev 3-term recurrence x_{j+1} = 2cos(th) x_j - x_{j-1} then runs
// FORWARD (j=8..15) and BACKWARD (j=6..0), so max drift distance is 8 steps
// -- same numerics as the validated CHUNK=8 version. Envelope frozen at t7.
// ---------------------------------------------------------------------------
struct Osc {
    float c2, cd, sd;      // wave-uniform (SGPR via s_load)
    float cA, sA;          // phase at j=7
    float wb;              // frozen weighted bell
};

__device__ __forceinline__ void osc_setup(const float* __restrict__ b,
                                          float tm, float tnm, float sig,
                                          Osc& o)
{
    const float f = b[0];
    o.cd = b[1];
    o.sd = b[2];
    o.c2 = b[3];

    const float hi  = f * tm;
    const float lo  = fmaf(f, tm, -hi);            // exact residual of f*tm
    const float rev = (hi - floorf(hi)) + lo + sig;
    o.cA = __builtin_amdgcn_cosf(rev);             // cos(2*pi*rev)
    o.sA = __builtin_amdgcn_sinf(rev);

    const float a = fmaf(b[4], tnm, b[5]);
    o.wb = __builtin_amdgcn_rsqf(fmaf(a, a, 1.0f)) * b[6];
}

// Accumulate AC[j] += wb*cos(A_j), AS[j] += wb*sin(A_j) for 8 oscillators
// (2 quads) over the 16-sample chunk, midpoint-split Chebyshev.
__device__ __forceinline__ void bank_accum(const float* __restrict__ base,
                                           float tm, float tnm, float sig,
                                           float* __restrict__ AC,
                                           float* __restrict__ AS)
{
#pragma unroll 1
    for (int q = 0; q < QH; ++q) {
        const float* B = base + q * 32;
        Osc o0, o1, o2, o3;
        osc_setup(B +  0, tm, tnm, sig, o0);
        osc_setup(B +  8, tm, tnm, sig, o1);
        osc_setup(B + 16, tm, tnm, sig, o2);
        osc_setup(B + 24, tm, tnm, sig, o3);

        // ---- forward chain: x0 = val(7), x1 = val(8) ----
#define FINIT(N)                                                        \
        float x0c##N = o##N.cA, x0s##N = o##N.sA;                       \
        float x1c##N = fmaf(-o##N.sA, o##N.sd, o##N.cA * o##N.cd);      \
        float x1s##N = fmaf( o##N.sA, o##N.cd, o##N.cA * o##N.sd);
        FINIT(0) FINIT(1) FINIT(2) FINIT(3)
#undef FINIT
#pragma unroll
        for (int jj = 0; jj < 9; ++jj) {
            const int j = 7 + jj;
#define FSTEP(N)                                                        \
            {                                                           \
                AC[j] = fmaf(o##N.wb, x0c##N, AC[j]);                   \
                AS[j] = fmaf(o##N.wb, x0s##N, AS[j]);                   \
                if (jj < 8) {                                           \
                    const float nc = fmaf(o##N.c2, x1c##N, -x0c##N);    \
                    x0c##N = x1c##N; x1c##N = nc;                       \
                    const float ns = fmaf(o##N.c2, x1s##N, -x0s##N);    \
                    x0s##N = x1s##N; x1s##N = ns;                       \
                }                                                       \
            }
            FSTEP(0) FSTEP(1) FSTEP(2) FSTEP(3)
#undef FSTEP
        }

        // ---- backward chain: cur = val(6), prev = val(7) ----
#define BINIT(N)                                                        \
        x1c##N = o##N.cA; x1s##N = o##N.sA;                             \
        x0c##N = fmaf( o##N.sA, o##N.sd, o##N.cA * o##N.cd);            \
        x0s##N = fmaf(-o##N.cA, o##N.sd, o##N.sA * o##N.cd);
        BINIT(0) BINIT(1) BINIT(2) BINIT(3)
#undef BINIT
#pragma unroll
        for (int jj = 0; jj < 7; ++jj) {
            const int j = 6 - jj;
#define BSTEP(N)                                                        \
            {                                                           \
                AC[j] = fmaf(o##N.wb, x0c##N, AC[j]);                   \
                AS[j] = fmaf(o##N.wb, x0s##N, AS[j]);                   \
                if (jj < 6) {                                           \
                    const float nc = fmaf(o##N.c2, x0c##N, -x1c##N);    \
                    x1c##N = x0c##N; x0c##N = nc;                       \
                    const float ns = fmaf(o##N.c2, x0s##N, -x1s##N);    \
                    x1s##N = x0s##N; x0s##N = ns;                       \
                }                                                       \
            }
            BSTEP(0) BSTEP(1) BSTEP(2) BSTEP(3)
#undef BSTEP
        }
    }
}

// ---------------------------------------------------------------------------
// Main kernel: block = 8 waves = 64 chunks x 16 samples = 1024 samples.
// Wave p handles frequency-group p of each bank (8 sorted oscillators,
// wave-uniform bank pointer -> s_load path). Owner-thread mapping for the
// cross-wave combines: thread tau owns samples {2tau, 2tau+1}; it computes
// ONE cos/sin pair of the modulator per sample and the final coalesced store.
//
// Carrier FM factorization + group-fbar jitter correction:
//   out_j = cm*S + sm*C + fbar_c*d2p_j*(cm*C - sm*S)
//   mod_j = Cm - fbar_m*d2p_j*Sm
// ---------------------------------------------------------------------------
__global__ void __launch_bounds__(512, 4) fm_main_kernel(
    const float* __restrict__ t,
    const float* __restrict__ banks,
    const float* __restrict__ scalars,
    float* __restrict__ out, int T)
{
    const int tid = threadIdx.x;
    const int c   = tid & 63;                                   // chunk lane
    const int p   = __builtin_amdgcn_readfirstlane(tid >> 6);   // wave id 0..7
    const int i0  = (blockIdx.x * 64 + c) * CHUNK;              // sample base

    __shared__ float pbuf[NSPLIT][64][CHUNK + 1];   // partials (mod, then carrier)
    __shared__ float cmb[64][CHUNK + 1];            // cos(mod)
    __shared__ float smb[64][CHUNK + 1];            // sin(mod)

    const float sig     = scalars[0];
    const float invtmax = scalars[1];
    const float dt      = scalars[2];
    const float fbm     = scalars[3 + p];           // mod group mean freq
    const float fbc     = scalars[3 + 8 + p];       // carrier group mean freq

    // load the 16 sample times; reference point = midpoint sample j=7
    float tm;
    float d2p[CHUNK];
    {
        const float4 ta = *reinterpret_cast<const float4*>(t + i0);
        const float4 tb = *reinterpret_cast<const float4*>(t + i0 + 4);
        const float4 tc = *reinterpret_cast<const float4*>(t + i0 + 8);
        const float4 td = *reinterpret_cast<const float4*>(t + i0 + 12);
        const float tj[CHUNK] = {ta.x, ta.y, ta.z, ta.w, tb.x, tb.y, tb.z, tb.w,
                                 tc.x, tc.y, tc.z, tc.w, td.x, td.y, td.z, td.w};
        tm = tj[7];
        // 2*pi * (t_j - (tm + (j-7)*dt)): f32 rounding jitter, radians per Hz
#pragma unroll
        for (int j = 0; j < CHUNK; ++j)
            d2p[j] = TWO_PI_F * fmaf(-(float)(j - 7), dt, tj[j] - tm);
    }
    const float tnm = fmaf(tm, invtmax, -0.5f);

    float AC[CHUNK], AS[CHUNK];
#pragma unroll
    for (int j = 0; j < CHUNK; ++j) { AC[j] = 0.0f; AS[j] = 0.0f; }

    // ---------------- modulator bank (group p: 8 sorted osc) ----------------
    bank_accum(banks + (p * 8) * 8, tm, tnm, sig, AC, AS);

    // publish jitter-corrected partial mod
#pragma unroll
    for (int j = 0; j < CHUNK; ++j)
        pbuf[p][c][j] = fmaf(-fbm * d2p[j], AS[j], AC[j]);
    __syncthreads();

    // owner-thread combine: thread tau owns samples {2tau, 2tau+1}
    {
        const int cc = tid >> 3;
        const int j0 = (tid & 7) * 2;
#pragma unroll
        for (int q2 = 0; q2 < 2; ++q2) {
            const int jj = j0 + q2;
            float m = pbuf[0][cc][jj];
#pragma unroll
            for (int w = 1; w < NSPLIT; ++w)
                m += pbuf[w][cc][jj];
            const float mrev = m * INV2PI_F;
            cmb[cc][jj] = __builtin_amdgcn_cosf(mrev);
            smb[cc][jj] = __builtin_amdgcn_sinf(mrev);
        }
    }
    __syncthreads();

    // ---------------- carrier bank (group p: 8 sorted osc) ------------------
#pragma unroll
    for (int j = 0; j < CHUNK; ++j) { AC[j] = 0.0f; AS[j] = 0.0f; }

    bank_accum(banks + (KOSC + p * 8) * 8, tm, tnm, sig, AC, AS);

    // epilogue: FM rotation + group-fbar jitter correction (cm/sm from LDS)
#pragma unroll
    for (int j = 0; j < CHUNK; ++j) {
        const float cmv = cmb[c][j];
        const float smv = smb[c][j];
        float u = cmv * AS[j];
        u = fmaf(smv, AC[j], u);
        float v = cmv * AC[j];
        v = fmaf(-smv, AS[j], v);
        pbuf[p][c][j] = fmaf(fbc * d2p[j], v, u);
    }
    __syncthreads();

    // owner-thread final combine; coalesced float2 store (sample = 2*tid)
    {
        const int cc = tid >> 3;
        const int j0 = (tid & 7) * 2;
        float o0v = pbuf[0][cc][j0];
        float o1v = pbuf[0][cc][j0 + 1];
#pragma unroll
        for (int w = 1; w < NSPLIT; ++w) {
            o0v += pbuf[w][cc][j0];
            o1v += pbuf[w][cc][j0 + 1];
        }
        *reinterpret_cast<float2*>(out + blockIdx.x * 1024 + tid * 2) =
            make_float2(o0v, o1v);
    }
}

// ---------------------------------------------------------------------------
extern "C" void kernel_launch(void* const* d_in, const int* in_sizes, int n_in,
                              void* d_out, int out_size, void* d_ws, size_t ws_size,
                              hipStream_t stream) {
    // setup_inputs() order:
    // 0:t 1:carrier_fq 2:carrier_weight 3:mod_fq 4:mod_weight 5:phase_offset
    // 6:carrier_env_slope 7:carrier_env_offset 8:mod_env_slope 9:mod_env_offset
    const float* t   = (const float*)d_in[0];
    const float* cfq = (const float*)d_in[1];
    const float* cw  = (const float*)d_in[2];
    const float* mfq = (const float*)d_in[3];
    const float* mw  = (const float*)d_in[4];
    const float* po  = (const float*)d_in[5];
    const float* ces = (const float*)d_in[6];
    const float* ceo = (const float*)d_in[7];
    const float* mes = (const float*)d_in[8];
    const float* meo = (const float*)d_in[9];
    const int T = in_sizes[0];

    float* banks   = (float*)d_ws;                       // 128 osc * 8 floats
    float* scalars = banks + 2 * KOSC * 8;               // 3 + 16 floats

    precompute_kernel<<<1, 2 * KOSC, 0, stream>>>(t, T, cfq, cw, mfq, mw, po,
                                                  ces, ceo, mes, meo,
                                                  banks, scalars);

    // one block = 8 waves = 64 chunks of 16 samples = 1024 samples
    const int grid = T / (CHUNK * 64);        // 1024 blocks for T = 1<<20
    fm_main_kernel<<<grid, 512, 0, stream>>>(t, banks, scalars,
                                             (float*)d_out, T);
}

// Round 9
// 31.704 us; speedup vs baseline: 1.0919x; 1.0513x over previous
//
#include <hip/hip_runtime.h>
#include <math.h>

#define KOSC 64
#define CHUNK 16                   // samples per chunk (per lane)
#define QH 4                       // quads per thread (4*4 = 16 osc, one bank)
#define TWO_PI_F  6.28318530717958647692f
#define INV2PI_F  0.15915494309189533577f
#define MIN_SLOPE -2.0f
#define MAX_SLOPE  8.0f

// ---------------------------------------------------------------------------
// Wave-wide (64-lane) reductions for the softmax in the precompute kernel.
// ---------------------------------------------------------------------------
__device__ __forceinline__ float wave_reduce_max(float v) {
#pragma unroll
    for (int off = 32; off > 0; off >>= 1)
        v = fmaxf(v, __shfl_xor(v, off, 64));
    return v;
}
__device__ __forceinline__ float wave_reduce_sum(float v) {
#pragma unroll
    for (int off = 32; off > 0; off >>= 1)
        v += __shfl_xor(v, off, 64);
    return v;
}

// ---------------------------------------------------------------------------
// Precompute. 128 threads = 2 waves (wave0 = modulator, wave1 = carrier).
// Each bank's 64 oscillators are SORTED BY FREQUENCY (rank-by-count); groups
// of 16 sorted oscillators share a mean frequency fbar used for the
// first-order time-jitter correction (residual 2*pi*|f-fbar|*~1.3e-6 <=
// ~1e-3 rad, weighted ~5e-4).
// banks[slot*8 + c]: c = {f, cd, sd, 2cd, s, s*off, w, 0}  (slot: mod 0..63
// sorted, carrier 64..127 sorted)
// scalars = { sig(rev), 1/tmax, dt, fbar[8] }  (4 mod groups, 4 carrier)
// ---------------------------------------------------------------------------
__global__ void precompute_kernel(
    const float* __restrict__ t, int T,
    const float* __restrict__ cfq, const float* __restrict__ cwt,
    const float* __restrict__ mfq, const float* __restrict__ mwt,
    const float* __restrict__ po,
    const float* __restrict__ ces, const float* __restrict__ ceo,
    const float* __restrict__ mes, const float* __restrict__ meo,
    float* __restrict__ banks, float* __restrict__ scalars)
{
    const int k    = threadIdx.x;     // 0..127
    const int bank = k >> 6;          // 0 = modulator, 1 = carrier
    const int idx  = k & 63;

    const float fq = bank ? cfq[idx] : mfq[idx];
    const float wt = bank ? cwt[idx] : mwt[idx];
    const float sl = bank ? ces[idx] : mes[idx];
    const float of = bank ? ceo[idx] : meo[idx];

    // per-wave softmax over the 64 weights of this bank (order-independent)
    const float mx = wave_reduce_max(wt);
    const float ex = expf(wt - mx);
    const float sm = wave_reduce_sum(ex);
    const float w  = ex / sm;

    // envelope constants
    const float sg   = 1.0f / (1.0f + expf(-sl));
    const float s    = exp2f(sg * (MAX_SLOPE - MIN_SLOPE) + MIN_SLOPE);
    const float offv = tanhf(of) * 0.5f;

    const float dt   = t[1] - t[0];           // t[0]==0 -> exact
    const float tmax = t[T - 1];

    // rotation constants in f64 (one-time cost)
    const double th = (double)TWO_PI_F * (double)fq * (double)dt;
    const float cd  = (float)cos(th);
    const float sd  = (float)sin(th);

    // rank of this oscillator within its bank, sorted by frequency ascending
    int rank = 0;
#pragma unroll 1
    for (int j = 0; j < 64; ++j) {
        const float fj = __shfl(fq, j, 64);
        if (fj < fq || (fj == fq && j < idx)) ++rank;
    }

    float* B = banks + (bank * 64 + rank) * 8;
    B[0] = fq;
    B[1] = cd;
    B[2] = sd;
    B[3] = cd + cd;                  // Chebyshev coefficient 2cos(th)
    B[4] = s;
    B[5] = s * offv;
    B[6] = w;
    B[7] = 0.0f;

    if (k == 0) {
        scalars[0] = 1.0f / (1.0f + expf(-po[0]));  // phase offset, REVOLUTIONS
        scalars[1] = 1.0f / tmax;
        scalars[2] = dt;
    }
    __syncthreads();

    // group mean frequencies: 8 groups of 16 sorted oscillators
    if (k < 8) {
        const float* G = banks + (k * 16) * 8;
        float fs = 0.0f;
#pragma unroll
        for (int i = 0; i < 16; ++i) fs += G[i * 8];
        scalars[3 + k] = fs * (1.0f / 16.0f);
    }
}

// ---------------------------------------------------------------------------
// Oscillator chunk state. Trig initialized at the chunk MIDPOINT sample j=7
// (exact Dekker split of f*t7 + Sterbenz frac, hw trig in revolutions); the
// Chebyshev 3-term recurrence x_{j+1} = 2cos(th) x_j - x_{j-1} runs FORWARD
// (j=8..15) and BACKWARD (j=6..0) -> max drift 8 steps. Envelope frozen at t7.
// ---------------------------------------------------------------------------
struct Osc {
    float c2, cd, sd;      // wave-uniform (SGPR via s_load)
    float cA, sA;          // phase at j=7
    float wb;              // frozen weighted bell
};

__device__ __forceinline__ void osc_setup(const float* __restrict__ b,
                                          float tm, float tnm, float sig,
                                          Osc& o)
{
    const float f = b[0];
    o.cd = b[1];
    o.sd = b[2];
    o.c2 = b[3];

    const float hi  = f * tm;
    const float lo  = fmaf(f, tm, -hi);            // exact residual of f*tm
    const float rev = (hi - floorf(hi)) + lo + sig;
    o.cA = __builtin_amdgcn_cosf(rev);             // cos(2*pi*rev)
    o.sA = __builtin_amdgcn_sinf(rev);

    const float a = fmaf(b[4], tnm, b[5]);
    o.wb = __builtin_amdgcn_rsqf(fmaf(a, a, 1.0f)) * b[6];
}

// Accumulate AC[j] += wb*cos(A_j), AS[j] += wb*sin(A_j) for 16 oscillators
// (4 quads) over the 16-sample chunk, midpoint-split Chebyshev.
__device__ __forceinline__ void bank_accum(const float* __restrict__ base,
                                           float tm, float tnm, float sig,
                                           float* __restrict__ AC,
                                           float* __restrict__ AS)
{
#pragma unroll 1
    for (int q = 0; q < QH; ++q) {
        const float* B = base + q * 32;
        Osc o0, o1, o2, o3;
        osc_setup(B +  0, tm, tnm, sig, o0);
        osc_setup(B +  8, tm, tnm, sig, o1);
        osc_setup(B + 16, tm, tnm, sig, o2);
        osc_setup(B + 24, tm, tnm, sig, o3);

        // ---- forward chain: x0 = val(7), x1 = val(8) ----
#define FINIT(N)                                                        \
        float x0c##N = o##N.cA, x0s##N = o##N.sA;                       \
        float x1c##N = fmaf(-o##N.sA, o##N.sd, o##N.cA * o##N.cd);      \
        float x1s##N = fmaf( o##N.sA, o##N.cd, o##N.cA * o##N.sd);
        FINIT(0) FINIT(1) FINIT(2) FINIT(3)
#undef FINIT
#pragma unroll
        for (int jj = 0; jj < 9; ++jj) {
            const int j = 7 + jj;
#define FSTEP(N)                                                        \
            {                                                           \
                AC[j] = fmaf(o##N.wb, x0c##N, AC[j]);                   \
                AS[j] = fmaf(o##N.wb, x0s##N, AS[j]);                   \
                if (jj < 8) {                                           \
                    const float nc = fmaf(o##N.c2, x1c##N, -x0c##N);    \
                    x0c##N = x1c##N; x1c##N = nc;                       \
                    const float ns = fmaf(o##N.c2, x1s##N, -x0s##N);    \
                    x0s##N = x1s##N; x1s##N = ns;                       \
                }                                                       \
            }
            FSTEP(0) FSTEP(1) FSTEP(2) FSTEP(3)
#undef FSTEP
        }

        // ---- backward chain: cur = val(6), prev = val(7) ----
#define BINIT(N)                                                        \
        x1c##N = o##N.cA; x1s##N = o##N.sA;                             \
        x0c##N = fmaf( o##N.sA, o##N.sd, o##N.cA * o##N.cd);            \
        x0s##N = fmaf(-o##N.cA, o##N.sd, o##N.sA * o##N.cd);
        BINIT(0) BINIT(1) BINIT(2) BINIT(3)
#undef BINIT
#pragma unroll
        for (int jj = 0; jj < 7; ++jj) {
            const int j = 6 - jj;
#define BSTEP(N)                                                        \
            {                                                           \
                AC[j] = fmaf(o##N.wb, x0c##N, AC[j]);                   \
                AS[j] = fmaf(o##N.wb, x0s##N, AS[j]);                   \
                if (jj < 6) {                                           \
                    const float nc = fmaf(o##N.c2, x0c##N, -x1c##N);    \
                    x1c##N = x0c##N; x0c##N = nc;                       \
                    const float ns = fmaf(o##N.c2, x0s##N, -x1s##N);    \
                    x1s##N = x0s##N; x0s##N = ns;                       \
                }                                                       \
            }
            BSTEP(0) BSTEP(1) BSTEP(2) BSTEP(3)
#undef BSTEP
        }
    }
}

// ---------------------------------------------------------------------------
// Main kernel: block = 8 waves, 64 chunks x 16 samples = 1024 samples.
// BANK-PARALLEL wave specialization: waves 0-3 accumulate the MODULATOR bank
// (16 sorted osc each), waves 4-7 concurrently accumulate the CARRIER bank --
// the FM rotation needs cos/sin(mod) only at the very end, so the banks'
// 2 fma/osc/sample streams overlap instead of serializing, and the kernel
// has ONE barrier instead of three.
//
// Published partials (jitter folded in, fbar = group mean freq):
//   mod wave p:      pM = AC - fbar*d2p*AS
//   carrier wave p:  pC = (S', C') = (AS + fbar*d2p*AC, AC - fbar*d2p*AS)
// Owner thread tau (2 samples): m = sum pM; cm,sm = trig(m);
//   out = cm*sum(S') + sm*sum(C')    -- coalesced float2 store.
// ---------------------------------------------------------------------------
__global__ void __launch_bounds__(512) fm_main_kernel(
    const float* __restrict__ t,
    const float* __restrict__ banks,
    const float* __restrict__ scalars,
    float* __restrict__ out, int T)
{
    const int tid = threadIdx.x;
    const int c   = tid & 63;                                   // chunk lane
    const int p   = __builtin_amdgcn_readfirstlane(tid >> 6);   // wave id 0..7
    const int i0  = (blockIdx.x * 64 + c) * CHUNK;              // sample base

    __shared__ float  pM[4][64][CHUNK + 2];       // modulator partials
    __shared__ float2 pC[4][64][CHUNK + 2];       // carrier (S', C') partials

    const float sig     = scalars[0];
    const float invtmax = scalars[1];
    const float dt      = scalars[2];
    const float fb      = scalars[3 + p];         // this wave's group mean freq

    // load the 16 sample times; reference point = midpoint sample j=7
    float tm;
    float d2p[CHUNK];
    {
        const float4 ta = *reinterpret_cast<const float4*>(t + i0);
        const float4 tb = *reinterpret_cast<const float4*>(t + i0 + 4);
        const float4 tc = *reinterpret_cast<const float4*>(t + i0 + 8);
        const float4 td = *reinterpret_cast<const float4*>(t + i0 + 12);
        const float tj[CHUNK] = {ta.x, ta.y, ta.z, ta.w, tb.x, tb.y, tb.z, tb.w,
                                 tc.x, tc.y, tc.z, tc.w, td.x, td.y, td.z, td.w};
        tm = tj[7];
        // 2*pi * (t_j - (tm + (j-7)*dt)): f32 rounding jitter, radians per Hz
#pragma unroll
        for (int j = 0; j < CHUNK; ++j)
            d2p[j] = TWO_PI_F * fmaf(-(float)(j - 7), dt, tj[j] - tm);
    }
    const float tnm = fmaf(tm, invtmax, -0.5f);

    float AC[CHUNK], AS[CHUNK];
#pragma unroll
    for (int j = 0; j < CHUNK; ++j) { AC[j] = 0.0f; AS[j] = 0.0f; }

    // this wave's 16 sorted oscillators (slots 16p..16p+15: p<4 -> modulator,
    // p>=4 -> carrier). Wave-uniform pointer -> s_load path.
    bank_accum(banks + (p * 16) * 8, tm, tnm, sig, AC, AS);

    // publish jitter-folded partials
    if (p < 4) {
#pragma unroll
        for (int j = 0; j < CHUNK; ++j)
            pM[p][c][j] = fmaf(-fb * d2p[j], AS[j], AC[j]);
    } else {
#pragma unroll
        for (int j = 0; j < CHUNK; ++j) {
            const float fd = fb * d2p[j];
            pC[p - 4][c][j] = make_float2(fmaf( fd, AC[j], AS[j]),
                                          fmaf(-fd, AS[j], AC[j]));
        }
    }
    __syncthreads();

    // owner-thread epilogue: thread tau owns samples {2tau, 2tau+1}
    {
        const int cc = tid >> 3;
        const int j0 = (tid & 7) * 2;

        // modulator sum -> one cm/sm pair per sample
        float m0 = pM[0][cc][j0],     m1 = pM[0][cc][j0 + 1];
#pragma unroll
        for (int w = 1; w < 4; ++w) {
            m0 += pM[w][cc][j0];
            m1 += pM[w][cc][j0 + 1];
        }
        const float cm0 = __builtin_amdgcn_cosf(m0 * INV2PI_F);
        const float sm0 = __builtin_amdgcn_sinf(m0 * INV2PI_F);
        const float cm1 = __builtin_amdgcn_cosf(m1 * INV2PI_F);
        const float sm1 = __builtin_amdgcn_sinf(m1 * INV2PI_F);

        // carrier sums: (S'_{j0}, C'_{j0}, S'_{j0+1}, C'_{j0+1}) per wave
        float4 a = *reinterpret_cast<const float4*>(&pC[0][cc][j0]);
#pragma unroll
        for (int w = 1; w < 4; ++w) {
            const float4 b = *reinterpret_cast<const float4*>(&pC[w][cc][j0]);
            a.x += b.x; a.y += b.y; a.z += b.z; a.w += b.w;
        }

        const float o0 = fmaf(cm0, a.x, sm0 * a.y);
        const float o1 = fmaf(cm1, a.z, sm1 * a.w);
        *reinterpret_cast<float2*>(out + blockIdx.x * 1024 + tid * 2) =
            make_float2(o0, o1);
    }
}

// ---------------------------------------------------------------------------
extern "C" void kernel_launch(void* const* d_in, const int* in_sizes, int n_in,
                              void* d_out, int out_size, void* d_ws, size_t ws_size,
                              hipStream_t stream) {
    // setup_inputs() order:
    // 0:t 1:carrier_fq 2:carrier_weight 3:mod_fq 4:mod_weight 5:phase_offset
    // 6:carrier_env_slope 7:carrier_env_offset 8:mod_env_slope 9:mod_env_offset
    const float* t   = (const float*)d_in[0];
    const float* cfq = (const float*)d_in[1];
    const float* cw  = (const float*)d_in[2];
    const float* mfq = (const float*)d_in[3];
    const float* mw  = (const float*)d_in[4];
    const float* po  = (const float*)d_in[5];
    const float* ces = (const float*)d_in[6];
    const float* ceo = (const float*)d_in[7];
    const float* mes = (const float*)d_in[8];
    const float* meo = (const float*)d_in[9];
    const int T = in_sizes[0];

    float* banks   = (float*)d_ws;                       // 128 osc * 8 floats
    float* scalars = banks + 2 * KOSC * 8;               // 3 + 8 floats

    precompute_kernel<<<1, 2 * KOSC, 0, stream>>>(t, T, cfq, cw, mfq, mw, po,
                                                  ces, ceo, mes, meo,
                                                  banks, scalars);

    // one block = 8 waves; waves split banks, lanes split samples
    const int grid = T / (CHUNK * 64);        // 1024 blocks for T = 1<<20
    fm_main_kernel<<<grid, 512, 0, stream>>>(t, banks, scalars,
                                             (float*)d_out, T);
}

// Round 11
// 23.968 us; speedup vs baseline: 1.4443x; 1.3228x over previous
//
#include <hip/hip_runtime.h>
#include <math.h>

#define KOSC 64
#define CHUNK 16
#define TWO_PI_F  6.28318530717958647692f
#define INV2PI_F  0.15915494309189533577f
#define TWO_PI_D  6.283185307179586476925286766559
#define MIN_SLOPE -2.0f
#define MAX_SLOPE  8.0f

typedef _Float16 v8h __attribute__((ext_vector_type(8)));
typedef float    v4f __attribute__((ext_vector_type(4)));

// gfx950 intrinsic (K=32, A/B = 8 x f16, C/D = 4 x f32). Called directly —
// no __has_builtin gate (it returns false in the HIP host pass; round-10 bug).
#define MFMA_F16(a, b, c) \
    __builtin_amdgcn_mfma_f32_16x16x32_f16((a), (b), (c), 0, 0, 0)

// ---------------------------------------------------------------------------
// ws layout:
//   [0,    2048): banksF4[128] float4 {f, s, s*off, w}  (0-63 mod, 64-127 car)
//   [2048, 2064): scalars {sig(rev), 1/tmax, dt}
//   [4096, 28672): Mfrag [6 tc][4 kk][64 lane][8] _Float16 (B-fragment order)
// ---------------------------------------------------------------------------

__device__ __forceinline__ float wave_reduce_max(float v) {
#pragma unroll
    for (int off = 32; off > 0; off >>= 1)
        v = fmaxf(v, __shfl_xor(v, off, 64));
    return v;
}
__device__ __forceinline__ float wave_reduce_sum(float v) {
#pragma unroll
    for (int off = 32; off > 0; off >>= 1)
        v += __shfl_xor(v, off, 64);
    return v;
}

// ---------------------------------------------------------------------------
// Precompute per-oscillator constants (128 threads = 2 waves; wave0 = mod,
// wave1 = carrier; per-wave softmax).
// ---------------------------------------------------------------------------
__global__ void precompute_kernel(
    const float* __restrict__ t, int T,
    const float* __restrict__ cfq, const float* __restrict__ cwt,
    const float* __restrict__ mfq, const float* __restrict__ mwt,
    const float* __restrict__ po,
    const float* __restrict__ ces, const float* __restrict__ ceo,
    const float* __restrict__ mes, const float* __restrict__ meo,
    float4* __restrict__ banksF4, float* __restrict__ scalars)
{
    const int k    = threadIdx.x;     // 0..127
    const int bank = k >> 6;
    const int idx  = k & 63;

    const float fq = bank ? cfq[idx] : mfq[idx];
    const float wt = bank ? cwt[idx] : mwt[idx];
    const float sl = bank ? ces[idx] : mes[idx];
    const float of = bank ? ceo[idx] : meo[idx];

    const float mx = wave_reduce_max(wt);
    const float ex = expf(wt - mx);
    const float sm = wave_reduce_sum(ex);
    const float w  = ex / sm;

    const float sg   = 1.0f / (1.0f + expf(-sl));
    const float s    = exp2f(sg * (MAX_SLOPE - MIN_SLOPE) + MIN_SLOPE);
    const float offv = tanhf(of) * 0.5f;

    banksF4[bank * 64 + idx] = make_float4(fq, s, s * offv, w);

    if (k == 0) {
        scalars[0] = 1.0f / (1.0f + expf(-po[0]));  // phase offset, REVOLUTIONS
        scalars[1] = 1.0f / t[T - 1];
        scalars[2] = t[1] - t[0];
    }
}

// ---------------------------------------------------------------------------
// Build the constant trig matrix M[256 kappa][96 col] in B-FRAGMENT order for
// mfma_f32_16x16x32_f16:  B[k][col], lane l holds col = l&15,
// k = kap0 + 8*(l>>4) + i (8 contiguous k per lane).
// Mfrag[tc][kk][l][i] = M[kap0(tc,kk) + 8*(l>>4) + i][16*tc + (l&15)],
//   kap0 = (tc<2 ? 0 : 128) + 32*kk   (mod cols read kappa 0..127, car 128..255)
// kappa = 2k   -> multiplies V[..][2k]   = wb*cos(A_k)
// kappa = 2k+1 -> multiplies V[..][2k+1] = wb*sin(A_k)
// Columns (j = col%16, jm7 = j-7):
//   tc0: Cm = cos-sum     tc1: Sfm = f*sin-sum     (modulator)
//   tc2: S  = sin-sum     tc3: C  = cos-sum
//   tc4: Sf = f*sin-sum   tc5: Cf = f*cos-sum      (carrier)
// Entries in f64: cos/sin(jm7 * 2*pi*f*dt), cast to fp16.
// ---------------------------------------------------------------------------
__global__ void prep_m_kernel(const float* __restrict__ t,
                              const float4* __restrict__ banksF4,
                              _Float16* __restrict__ Mfrag)
{
    const int tc  = blockIdx.x;                    // 0..5
    const int kk  = threadIdx.x >> 6;              // 0..3
    const int l   = threadIdx.x & 63;
    const int q   = l >> 4, cp = l & 15;
    const double jm7 = (double)(cp - 7);
    const double dt  = (double)(t[1] - t[0]);
    const int kap0 = ((tc < 2) ? 0 : 128) + 32 * kk;

#pragma unroll
    for (int i = 0; i < 8; ++i) {
        const int kap  = kap0 + q * 8 + i;
        const int bank = kap >> 7;
        const int kidx = (kap & 127) >> 1;
        const int part = kap & 1;
        const float f  = banksF4[bank * 64 + kidx].x;

        const double ang = jm7 * (TWO_PI_D * (double)f * dt);
        const float cj = (float)cos(ang);
        const float sj = (float)sin(ang);

        float val = 0.0f;
        if (bank == 0) {
            if      (tc == 0) val = part ? -sj : cj;        // Cm
            else if (tc == 1) val = (part ? cj : sj) * f;   // Sfm
        } else {
            if      (tc == 2) val = part ? cj : sj;         // S
            else if (tc == 3) val = part ? -sj : cj;        // C
            else if (tc == 4) val = (part ? cj : sj) * f;   // Sf
            else if (tc == 5) val = (part ? -sj : cj) * f;  // Cf
        }
        Mfrag[(((tc * 4 + kk) * 64 + l) << 3) + i] = (_Float16)val;
    }
}

// ---------------------------------------------------------------------------
// Main kernel: block = 512 threads = 8 waves; 64 chunks x 16 samples = 1024
// samples per block.
// Phase 1: wave p computes phasors for its 16 oscillators (wave-uniform
//   consts -> s_load) at each lane's chunk midpoint tm = t[chunk*16+7]
//   (exact Dekker + Sterbenz frac + hw trig in revolutions), writes packed
//   fp16 (wb*cosA, wb*sinA) into V (LDS).
// Phase 2: 24 output tiles (4 chunk-tiles x 6 col-tiles), 3 per wave, each
//   4x v_mfma_f32_16x16x32_f16 over its bank's K=128 half of kappa.
//   A: row = l&15 (chunk in tile), k = 8*(l>>4)+i  (8 contiguous halves).
//   D: col = l&15, row = 4*(l>>4)+reg  [m89-verified mapping].
// Phase 3: owner thread (2 samples): jitter-corrected mod -> one trig pair
//   -> FM rotation + jitter -> coalesced float2 store.
// ---------------------------------------------------------------------------
__global__ void __launch_bounds__(512) fm_main_kernel(
    const float* __restrict__ t,
    const float4* __restrict__ banksF4,
    const float* __restrict__ scalars,
    const _Float16* __restrict__ Mfrag,
    float* __restrict__ out)
{
    // V rows padded to 132 words (264 halves, 528 B): keeps half8 loads 16B-
    // aligned; row-to-row bank offset 4 -> worst 2-way conflict (free, m136).
    __shared__ unsigned vlds[64 * 132];   // 33792 B
    __shared__ float    clds[64 * 98];    // 25088 B

    const int tid  = threadIdx.x;
    const int c    = tid & 63;                                  // lane / chunk
    const int p    = __builtin_amdgcn_readfirstlane(tid >> 6);  // wave 0..7
    const int base = blockIdx.x * 1024;

    const float sig     = scalars[0];
    const float invtmax = scalars[1];
    const float dtf     = scalars[2];

    // ---------------- phase 1: phasors ----------------
    {
        const float tm  = t[base + c * 16 + 7];
        const float tnm = fmaf(tm, invtmax, -0.5f);
        const float4* bb = banksF4 + p * 16;     // wave-uniform -> s_load
#pragma unroll
        for (int i = 0; i < 16; ++i) {
            const float4 cst = bb[i];            // {f, s, s*off, w}
            const float hi  = cst.x * tm;
            const float lo  = fmaf(cst.x, tm, -hi);      // exact residual
            const float rev = (hi - floorf(hi)) + lo + sig;
            const float cA  = __builtin_amdgcn_cosf(rev);
            const float sA  = __builtin_amdgcn_sinf(rev);
            const float a   = fmaf(cst.y, tnm, cst.z);
            const float wb  = __builtin_amdgcn_rsqf(fmaf(a, a, 1.0f)) * cst.w;
            union { _Float16 h[2]; unsigned u; } pk;
            pk.h[0] = (_Float16)(wb * cA);       // kappa = 2*(p*16+i)
            pk.h[1] = (_Float16)(wb * sA);       // kappa = 2*(p*16+i)+1
            vlds[c * 132 + p * 16 + i] = pk.u;
        }
    }
    __syncthreads();

    // ---------------- phase 2: MFMA ----------------
    {
        const int q = c >> 4, cp = c & 15;
        const _Float16* vh = reinterpret_cast<const _Float16*>(vlds);
#pragma unroll
        for (int n = 0; n < 3; ++n) {
            const int tile = p + 8 * n;          // 0..23
            const int tr = tile & 3, tc = tile >> 2;
            const int kbase = (tc < 2) ? 0 : 128;
            const _Float16* ap = vh + (16 * tr + cp) * 264 + kbase + q * 8;
            const _Float16* mp = Mfrag + (((tc * 4) * 64 + c) << 3);
            v4f acc = {0.0f, 0.0f, 0.0f, 0.0f};
#pragma unroll
            for (int kk = 0; kk < 4; ++kk) {
                const v8h a = *reinterpret_cast<const v8h*>(ap + kk * 32);
                const v8h b = *reinterpret_cast<const v8h*>(mp + kk * 512);
                acc = MFMA_F16(a, b, acc);
            }
#pragma unroll
            for (int i = 0; i < 4; ++i)
                clds[(16 * tr + 4 * q + i) * 98 + 16 * tc + cp] = acc[i];
        }
    }
    __syncthreads();

    // ---------------- phase 3: epilogue ----------------
    {
        const int cc = tid >> 3;                 // chunk
        const int j0 = (tid & 7) * 2;            // first of 2 samples
        const float tmc = t[base + cc * 16 + 7];
        const float2 tt = *reinterpret_cast<const float2*>(t + base + cc * 16 + j0);
        const float* Cr = clds + cc * 98 + j0;

        float o2[2];
#pragma unroll
        for (int e = 0; e < 2; ++e) {
            const float tje = e ? tt.y : tt.x;
            // 2*pi*(t_j - (tm + (j-7)*dt)): f32 rounding jitter, rad per Hz
            const float d2p = TWO_PI_F * fmaf(-(float)(j0 + e - 7), dtf, tje - tmc);
            const float Cm  = Cr[e],      Sfm = Cr[16 + e];
            const float S   = Cr[32 + e], Cc  = Cr[48 + e];
            const float Sf  = Cr[64 + e], Cf  = Cr[80 + e];

            const float m    = fmaf(-d2p, Sfm, Cm);          // modulator value
            const float mrev = m * INV2PI_F;
            const float cm = __builtin_amdgcn_cosf(mrev);
            const float sm = __builtin_amdgcn_sinf(mrev);

            const float u = fmaf(cm, S, sm * Cc);
            const float v = fmaf(cm, Cf, -(sm * Sf));
            o2[e] = fmaf(d2p, v, u);
        }
        *reinterpret_cast<float2*>(out + base + cc * 16 + j0) =
            make_float2(o2[0], o2[1]);
    }
}

// ---------------------------------------------------------------------------
extern "C" void kernel_launch(void* const* d_in, const int* in_sizes, int n_in,
                              void* d_out, int out_size, void* d_ws, size_t ws_size,
                              hipStream_t stream) {
    // setup_inputs() order:
    // 0:t 1:carrier_fq 2:carrier_weight 3:mod_fq 4:mod_weight 5:phase_offset
    // 6:carrier_env_slope 7:carrier_env_offset 8:mod_env_slope 9:mod_env_offset
    const float* t   = (const float*)d_in[0];
    const float* cfq = (const float*)d_in[1];
    const float* cw  = (const float*)d_in[2];
    const float* mfq = (const float*)d_in[3];
    const float* mw  = (const float*)d_in[4];
    const float* po  = (const float*)d_in[5];
    const float* ces = (const float*)d_in[6];
    const float* ceo = (const float*)d_in[7];
    const float* mes = (const float*)d_in[8];
    const float* meo = (const float*)d_in[9];
    const int T = in_sizes[0];

    float4*    banksF4 = (float4*)d_ws;
    float*     scalars = (float*)((char*)d_ws + 2048);
    _Float16*  Mfrag   = (_Float16*)((char*)d_ws + 4096);

    precompute_kernel<<<1, 128, 0, stream>>>(t, T, cfq, cw, mfq, mw, po,
                                             ces, ceo, mes, meo,
                                             banksF4, scalars);

    prep_m_kernel<<<6, 256, 0, stream>>>(t, banksF4, Mfrag);

    const int grid = T / 1024;                 // 1024 blocks for T = 1<<20
    fm_main_kernel<<<grid, 512, 0, stream>>>(t, banksF4, scalars, Mfrag,
                                             (float*)d_out);
}

// Round 12
// 18.750 us; speedup vs baseline: 1.8463x; 1.2783x over previous
//
#include <hip/hip_runtime.h>
#include <math.h>

#define KOSC 64
#define CHUNK 16
#define TWO_PI_F  6.28318530717958647692f
#define INV2PI_F  0.15915494309189533577f
#define MIN_SLOPE -2.0f
#define MAX_SLOPE  8.0f

typedef _Float16 v8h __attribute__((ext_vector_type(8)));
typedef float    v4f __attribute__((ext_vector_type(4)));

// gfx950 intrinsic (K=32, A/B = 8 x f16, C/D = 4 x f32).
#define MFMA_F16(a, b, c) \
    __builtin_amdgcn_mfma_f32_16x16x32_f16((a), (b), (c), 0, 0, 0)

// ---------------------------------------------------------------------------
// ws layout:
//   [0,    2048): banksF4[128] float4 {f, s, s*off, w}  (0-63 mod, 64-127 car)
//   [2048, 2064): scalars {sig(rev), 1/tmax, dt}
//   [4096, 28672): Mfrag [6 tc][4 kk][64 lane][8] _Float16 (B-fragment order)
// ---------------------------------------------------------------------------

__device__ __forceinline__ float wave_reduce_max(float v) {
#pragma unroll
    for (int off = 32; off > 0; off >>= 1)
        v = fmaxf(v, __shfl_xor(v, off, 64));
    return v;
}
__device__ __forceinline__ float wave_reduce_sum(float v) {
#pragma unroll
    for (int off = 32; off > 0; off >>= 1)
        v += __shfl_xor(v, off, 64);
    return v;
}

// ---------------------------------------------------------------------------
// ONE fused prep kernel (7 blocks x 256):
//  block 0, threads 0-127 (2 waves): per-oscillator constants + scalars
//    (wave0 = modulator softmax, wave1 = carrier softmax).
//  blocks 1-6: trig matrix M for column-tile tc = blockIdx.x-1, using the
//    RAW frequencies straight from the inputs (no dependency on block 0),
//    hw f32 trig in REVOLUTIONS (angle <= 0.2 rev -> no range reduction;
//    error ~1e-6, far below fp16 ulp). No f64 libm anywhere.
//
// M layout (B-fragment order for mfma_f32_16x16x32_f16; B[k][col], lane l
// holds col = l&15, k = kap0 + 8*(l>>4) + i):
//   Mfrag[tc][kk][l][i] = M[kap0(tc,kk) + 8*(l>>4) + i][16*tc + (l&15)]
//   kap0 = (tc<2 ? 0 : 128) + 32*kk
//   kappa = 2k -> multiplies wb*cos(A_k); 2k+1 -> wb*sin(A_k)
// Columns (j = col%16, jm7 = j-7):
//   tc0: Cm = cos-sum     tc1: Sfm = f*sin-sum     (modulator)
//   tc2: S  = sin-sum     tc3: C  = cos-sum
//   tc4: Sf = f*sin-sum   tc5: Cf = f*cos-sum      (carrier)
// ---------------------------------------------------------------------------
__global__ void prep_kernel(
    const float* __restrict__ t, int T,
    const float* __restrict__ cfq, const float* __restrict__ cwt,
    const float* __restrict__ mfq, const float* __restrict__ mwt,
    const float* __restrict__ po,
    const float* __restrict__ ces, const float* __restrict__ ceo,
    const float* __restrict__ mes, const float* __restrict__ meo,
    float4* __restrict__ banksF4, float* __restrict__ scalars,
    _Float16* __restrict__ Mfrag)
{
    if (blockIdx.x == 0) {
        const int k = threadIdx.x;
        if (k >= 128) return;
        const int bank = k >> 6;
        const int idx  = k & 63;

        const float fq = bank ? cfq[idx] : mfq[idx];
        const float wt = bank ? cwt[idx] : mwt[idx];
        const float sl = bank ? ces[idx] : mes[idx];
        const float of = bank ? ceo[idx] : meo[idx];

        const float mx = wave_reduce_max(wt);
        const float ex = expf(wt - mx);
        const float sm = wave_reduce_sum(ex);
        const float w  = ex / sm;

        const float sg   = 1.0f / (1.0f + expf(-sl));
        const float s    = exp2f(sg * (MAX_SLOPE - MIN_SLOPE) + MIN_SLOPE);
        const float offv = tanhf(of) * 0.5f;

        banksF4[bank * 64 + idx] = make_float4(fq, s, s * offv, w);

        if (k == 0) {
            scalars[0] = 1.0f / (1.0f + expf(-po[0]));  // phase offset, rev
            scalars[1] = 1.0f / t[T - 1];
            scalars[2] = t[1] - t[0];
        }
        return;
    }

    // ----- M-table blocks -----
    const int tc  = blockIdx.x - 1;                // 0..5
    const int kk  = threadIdx.x >> 6;              // 0..3
    const int l   = threadIdx.x & 63;
    const int q   = l >> 4, cp = l & 15;
    const float jm7 = (float)(cp - 7);
    const float dt  = t[1] - t[0];
    const int kap0 = ((tc < 2) ? 0 : 128) + 32 * kk;

#pragma unroll
    for (int i = 0; i < 8; ++i) {
        const int kap  = kap0 + q * 8 + i;
        const int bank = kap >> 7;
        const int kidx = (kap & 127) >> 1;
        const int part = kap & 1;
        const float f  = bank ? cfq[kidx] : mfq[kidx];   // raw input freq

        const float ang = jm7 * (f * dt);          // revolutions, |ang|<=0.2
        const float cj = __builtin_amdgcn_cosf(ang);
        const float sj = __builtin_amdgcn_sinf(ang);

        float val = 0.0f;
        if (bank == 0) {
            if      (tc == 0) val = part ? -sj : cj;        // Cm
            else if (tc == 1) val = (part ? cj : sj) * f;   // Sfm
        } else {
            if      (tc == 2) val = part ? cj : sj;         // S
            else if (tc == 3) val = part ? -sj : cj;        // C
            else if (tc == 4) val = (part ? cj : sj) * f;   // Sf
            else if (tc == 5) val = (part ? -sj : cj) * f;  // Cf
        }
        Mfrag[(((tc * 4 + kk) * 64 + l) << 3) + i] = (_Float16)val;
    }
}

// ---------------------------------------------------------------------------
// Main kernel: block = 512 threads = 8 waves; 64 chunks x 16 samples = 1024
// samples per block.  __launch_bounds__(512, 4): 4 waves/EU -> VGPR <= 128
// -> 2 blocks/CU with the 58.9 KB LDS footprint.
// Phase 1: wave p computes phasors for its 16 oscillators (wave-uniform
//   consts -> s_load) at each lane's chunk midpoint tm = t[chunk*16+7]
//   (exact Dekker + Sterbenz frac + hw trig in revolutions), writes packed
//   fp16 (wb*cosA, wb*sinA) into V (LDS).
// Phase 2: 24 output tiles (4 chunk-tiles x 6 col-tiles), 3 per wave, each
//   4x v_mfma_f32_16x16x32_f16 over its bank's K=128 half of kappa.
//   A: row = l&15 (chunk in tile), k = 8*(l>>4)+i (8 contiguous halves).
//   D: col = l&15, row = 4*(l>>4)+reg  [m89-verified mapping].
// Phase 3: owner thread (2 samples): jitter-corrected mod -> one trig pair
//   -> FM rotation + jitter -> coalesced float2 store.
// ---------------------------------------------------------------------------
__global__ void __launch_bounds__(512, 4) fm_main_kernel(
    const float* __restrict__ t,
    const float4* __restrict__ banksF4,
    const float* __restrict__ scalars,
    const _Float16* __restrict__ Mfrag,
    float* __restrict__ out)
{
    // V rows padded to 132 words (264 halves, 528 B): keeps half8 loads 16B-
    // aligned; row-to-row bank offset 4.
    __shared__ unsigned vlds[64 * 132];   // 33792 B
    __shared__ float    clds[64 * 98];    // 25088 B

    const int tid  = threadIdx.x;
    const int c    = tid & 63;                                  // lane / chunk
    const int p    = __builtin_amdgcn_readfirstlane(tid >> 6);  // wave 0..7
    const int base = blockIdx.x * 1024;

    const float sig     = scalars[0];
    const float invtmax = scalars[1];
    const float dtf     = scalars[2];

    // ---------------- phase 1: phasors ----------------
    {
        const float tm  = t[base + c * 16 + 7];
        const float tnm = fmaf(tm, invtmax, -0.5f);
        const float4* bb = banksF4 + p * 16;     // wave-uniform -> s_load
#pragma unroll
        for (int i = 0; i < 16; ++i) {
            const float4 cst = bb[i];            // {f, s, s*off, w}
            const float hi  = cst.x * tm;
            const float lo  = fmaf(cst.x, tm, -hi);      // exact residual
            const float rev = (hi - floorf(hi)) + lo + sig;
            const float cA  = __builtin_amdgcn_cosf(rev);
            const float sA  = __builtin_amdgcn_sinf(rev);
            const float a   = fmaf(cst.y, tnm, cst.z);
            const float wb  = __builtin_amdgcn_rsqf(fmaf(a, a, 1.0f)) * cst.w;
            union { _Float16 h[2]; unsigned u; } pk;
            pk.h[0] = (_Float16)(wb * cA);       // kappa = 2*(p*16+i)
            pk.h[1] = (_Float16)(wb * sA);       // kappa = 2*(p*16+i)+1
            vlds[c * 132 + p * 16 + i] = pk.u;
        }
    }
    __syncthreads();

    // ---------------- phase 2: MFMA ----------------
    {
        const int q = c >> 4, cp = c & 15;
        const _Float16* vh = reinterpret_cast<const _Float16*>(vlds);
#pragma unroll
        for (int n = 0; n < 3; ++n) {
            const int tile = p + 8 * n;          // 0..23
            const int tr = tile & 3, tc = tile >> 2;
            const int kbase = (tc < 2) ? 0 : 128;
            const _Float16* ap = vh + (16 * tr + cp) * 264 + kbase + q * 8;
            const _Float16* mp = Mfrag + (((tc * 4) * 64 + c) << 3);
            v4f acc = {0.0f, 0.0f, 0.0f, 0.0f};
#pragma unroll
            for (int kk = 0; kk < 4; ++kk) {
                const v8h a = *reinterpret_cast<const v8h*>(ap + kk * 32);
                const v8h b = *reinterpret_cast<const v8h*>(mp + kk * 512);
                acc = MFMA_F16(a, b, acc);
            }
#pragma unroll
            for (int i = 0; i < 4; ++i)
                clds[(16 * tr + 4 * q + i) * 98 + 16 * tc + cp] = acc[i];
        }
    }
    __syncthreads();

    // ---------------- phase 3: epilogue ----------------
    {
        const int cc = tid >> 3;                 // chunk
        const int j0 = (tid & 7) * 2;            // first of 2 samples
        const float tmc = t[base + cc * 16 + 7];
        const float2 tt = *reinterpret_cast<const float2*>(t + base + cc * 16 + j0);
        const float* Cr = clds + cc * 98 + j0;

        float o2[2];
#pragma unroll
        for (int e = 0; e < 2; ++e) {
            const float tje = e ? tt.y : tt.x;
            // 2*pi*(t_j - (tm + (j-7)*dt)): f32 rounding jitter, rad per Hz
            const float d2p = TWO_PI_F * fmaf(-(float)(j0 + e - 7), dtf, tje - tmc);
            const float Cm  = Cr[e],      Sfm = Cr[16 + e];
            const float S   = Cr[32 + e], Cc  = Cr[48 + e];
            const float Sf  = Cr[64 + e], Cf  = Cr[80 + e];

            const float m    = fmaf(-d2p, Sfm, Cm);          // modulator value
            const float mrev = m * INV2PI_F;
            const float cm = __builtin_amdgcn_cosf(mrev);
            const float sm = __builtin_amdgcn_sinf(mrev);

            const float u = fmaf(cm, S, sm * Cc);
            const float v = fmaf(cm, Cf, -(sm * Sf));
            o2[e] = fmaf(d2p, v, u);
        }
        *reinterpret_cast<float2*>(out + base + cc * 16 + j0) =
            make_float2(o2[0], o2[1]);
    }
}

// ---------------------------------------------------------------------------
extern "C" void kernel_launch(void* const* d_in, const int* in_sizes, int n_in,
                              void* d_out, int out_size, void* d_ws, size_t ws_size,
                              hipStream_t stream) {
    // setup_inputs() order:
    // 0:t 1:carrier_fq 2:carrier_weight 3:mod_fq 4:mod_weight 5:phase_offset
    // 6:carrier_env_slope 7:carrier_env_offset 8:mod_env_slope 9:mod_env_offset
    const float* t   = (const float*)d_in[0];
    const float* cfq = (const float*)d_in[1];
    const float* cw  = (const float*)d_in[2];
    const float* mfq = (const float*)d_in[3];
    const float* mw  = (const float*)d_in[4];
    const float* po  = (const float*)d_in[5];
    const float* ces = (const float*)d_in[6];
    const float* ceo = (const float*)d_in[7];
    const float* mes = (const float*)d_in[8];
    const float* meo = (const float*)d_in[9];
    const int T = in_sizes[0];

    float4*    banksF4 = (float4*)d_ws;
    float*     scalars = (float*)((char*)d_ws + 2048);
    _Float16*  Mfrag   = (_Float16*)((char*)d_ws + 4096);

    // single fused prep launch (block 0: constants; blocks 1-6: M table)
    prep_kernel<<<7, 256, 0, stream>>>(t, T, cfq, cw, mfq, mw, po,
                                       ces, ceo, mes, meo,
                                       banksF4, scalars, Mfrag);

    const int grid = T / 1024;                 // 1024 blocks for T = 1<<20
    fm_main_kernel<<<grid, 512, 0, stream>>>(t, banksF4, scalars, Mfrag,
                                             (float*)d_out);
}

// Round 13
// 17.615 us; speedup vs baseline: 1.9652x; 1.0644x over previous
//
#include <hip/hip_runtime.h>
#include <math.h>

#define KOSC 64
#define CHUNK 32
#define TWO_PI_F  6.28318530717958647692f
#define INV2PI_F  0.15915494309189533577f
#define MIN_SLOPE -2.0f
#define MAX_SLOPE  8.0f

typedef _Float16 v8h __attribute__((ext_vector_type(8)));
typedef float    v4f __attribute__((ext_vector_type(4)));

// gfx950 intrinsic (K=32, A/B = 8 x f16, C/D = 4 x f32).
#define MFMA_F16(a, b, c) \
    __builtin_amdgcn_mfma_f32_16x16x32_f16((a), (b), (c), 0, 0, 0)

// ---------------------------------------------------------------------------
// ws layout:
//   [0,    2048): banksF4[128] float4 {f, s, s*off, w}  (0-63 mod, 64-127 car)
//   [2048, 2064): scalars {sig(rev), 1/tmax, dt}
//   [4096, 53248): Mfrag [12 tcg][4 kk][64 lane][8] _Float16 (B-fragment order)
// ---------------------------------------------------------------------------

__device__ __forceinline__ float wave_reduce_max(float v) {
#pragma unroll
    for (int off = 32; off > 0; off >>= 1)
        v = fmaxf(v, __shfl_xor(v, off, 64));
    return v;
}
__device__ __forceinline__ float wave_reduce_sum(float v) {
#pragma unroll
    for (int off = 32; off > 0; off >>= 1)
        v += __shfl_xor(v, off, 64);
    return v;
}

// ---------------------------------------------------------------------------
// ONE fused prep kernel (13 blocks x 256):
//  block 0, threads 0-127 (2 waves): per-oscillator constants + scalars.
//  blocks 1-12: trig matrix M for column-tile-group tcg = blockIdx.x-1
//    (h = tcg/6 selects the j-half, tc = tcg%6 the quantity tile), using RAW
//    input frequencies (no dependency on block 0), hw f32 trig in REVOLUTIONS
//    (|ang| <= 0.34 rev -> exact-ish, far below fp16 ulp).
//
// M layout (B-fragment order for mfma_f32_16x16x32_f16; lane l holds
// col = l&15, k = kap0 + 8*(l>>4) + i):
//   Mfrag[tcg][kk][l][i] = M[kap0 + 8*(l>>4) + i][...]
//   kap0 = (tc<2 ? 0 : 128) + 32*kk
//   kappa = 2k -> multiplies wb*cos(A_k); 2k+1 -> wb*sin(A_k)
//   j within half: jm = (l&15) - 15 + 16*h   (chunk midpoint at j=15)
// Quantity tiles (per half):
//   tc0: Cm = cos-sum     tc1: Sfm = f*sin-sum     (modulator)
//   tc2: S  = sin-sum     tc3: C  = cos-sum
//   tc4: Sf = f*sin-sum   tc5: Cf = f*cos-sum      (carrier)
// ---------------------------------------------------------------------------
__global__ void prep_kernel(
    const float* __restrict__ t, int T,
    const float* __restrict__ cfq, const float* __restrict__ cwt,
    const float* __restrict__ mfq, const float* __restrict__ mwt,
    const float* __restrict__ po,
    const float* __restrict__ ces, const float* __restrict__ ceo,
    const float* __restrict__ mes, const float* __restrict__ meo,
    float4* __restrict__ banksF4, float* __restrict__ scalars,
    _Float16* __restrict__ Mfrag)
{
    if (blockIdx.x == 0) {
        const int k = threadIdx.x;
        if (k >= 128) return;
        const int bank = k >> 6;
        const int idx  = k & 63;

        const float fq = bank ? cfq[idx] : mfq[idx];
        const float wt = bank ? cwt[idx] : mwt[idx];
        const float sl = bank ? ces[idx] : mes[idx];
        const float of = bank ? ceo[idx] : meo[idx];

        const float mx = wave_reduce_max(wt);
        const float ex = expf(wt - mx);
        const float sm = wave_reduce_sum(ex);
        const float w  = ex / sm;

        const float sg   = 1.0f / (1.0f + expf(-sl));
        const float s    = exp2f(sg * (MAX_SLOPE - MIN_SLOPE) + MIN_SLOPE);
        const float offv = tanhf(of) * 0.5f;

        banksF4[bank * 64 + idx] = make_float4(fq, s, s * offv, w);

        if (k == 0) {
            scalars[0] = 1.0f / (1.0f + expf(-po[0]));  // phase offset, rev
            scalars[1] = 1.0f / t[T - 1];
            scalars[2] = t[1] - t[0];
        }
        return;
    }

    // ----- M-table blocks -----
    const int tcg = blockIdx.x - 1;                // 0..11
    const int h   = tcg / 6;
    const int tc  = tcg % 6;
    const int kk  = threadIdx.x >> 6;              // 0..3
    const int l   = threadIdx.x & 63;
    const int q   = l >> 4, cp = l & 15;
    const float jm  = (float)(cp - 15 + 16 * h);   // j - 15, j in this half
    const float dt  = t[1] - t[0];
    const int kap0 = ((tc < 2) ? 0 : 128) + 32 * kk;

#pragma unroll
    for (int i = 0; i < 8; ++i) {
        const int kap  = kap0 + q * 8 + i;
        const int bank = kap >> 7;
        const int kidx = (kap & 127) >> 1;
        const int part = kap & 1;
        const float f  = bank ? cfq[kidx] : mfq[kidx];   // raw input freq

        const float ang = jm * (f * dt);           // revolutions, |ang|<=0.34
        const float cj = __builtin_amdgcn_cosf(ang);
        const float sj = __builtin_amdgcn_sinf(ang);

        float val = 0.0f;
        if (bank == 0) {
            if      (tc == 0) val = part ? -sj : cj;        // Cm
            else if (tc == 1) val = (part ? cj : sj) * f;   // Sfm
        } else {
            if      (tc == 2) val = part ? cj : sj;         // S
            else if (tc == 3) val = part ? -sj : cj;        // C
            else if (tc == 4) val = (part ? cj : sj) * f;   // Sf
            else if (tc == 5) val = (part ? -sj : cj) * f;  // Cf
        }
        Mfrag[(((tcg * 4 + kk) * 64 + l) << 3) + i] = (_Float16)val;
    }
}

// ---------------------------------------------------------------------------
// Main kernel: block = 512 threads = 8 waves; 64 chunks x 32 samples = 2048
// samples per block; grid = 512 = exactly 2 blocks/CU (one dispatch round).
// Phase 1: wave p computes phasors for its 16 oscillators (wave-uniform
//   consts -> s_load) at each lane's chunk midpoint tm = t[chunk*32+15]
//   (exact Dekker + Sterbenz frac + hw trig in revolutions), writes packed
//   fp16 (wb*cosA, wb*sinA) into V (LDS) as uint2 pairs. Phasor count per
//   block is unchanged vs CHUNK=16 but serves 2x the samples (M-matrix
//   scheme has NO error growth with chunk length - entries are exact trig).
// Phases 2/3 run TWICE (j-halves h=0,1) reusing the same clds:
//   ph2(h): 24 tiles (4 chunk-tiles x 6 quantity-tiles), 3/wave, 4 MFMA each.
//   ph3(h): owner thread (2 samples): jitter-corrected mod -> one trig pair
//           -> FM rotation + jitter -> coalesced float2 store.
// ---------------------------------------------------------------------------
__global__ void __launch_bounds__(512, 4) fm_main_kernel(
    const float* __restrict__ t,
    const float4* __restrict__ banksF4,
    const float* __restrict__ scalars,
    const _Float16* __restrict__ Mfrag,
    float* __restrict__ out)
{
    // V rows padded to 132 words (264 halves, 528 B): 16B-aligned half8 loads.
    __shared__ unsigned vlds[64 * 132];   // 33792 B
    __shared__ float    clds[64 * 98];    // 25088 B  (one j-half at a time)

    const int tid  = threadIdx.x;
    const int c    = tid & 63;                                  // lane / chunk
    const int p    = __builtin_amdgcn_readfirstlane(tid >> 6);  // wave 0..7
    const int base = blockIdx.x * 2048;

    const float sig     = scalars[0];
    const float invtmax = scalars[1];
    const float dtf     = scalars[2];

    // ---------------- phase 1: phasors ----------------
    {
        const float tm  = t[base + c * 32 + 15];
        const float tnm = fmaf(tm, invtmax, -0.5f);
        const float4* bb = banksF4 + p * 16;     // wave-uniform -> s_load
        uint2* vrow = reinterpret_cast<uint2*>(vlds + c * 132 + p * 16);
#pragma unroll
        for (int i = 0; i < 8; ++i) {
            unsigned pk2[2];
#pragma unroll
            for (int e = 0; e < 2; ++e) {
                const float4 cst = bb[2 * i + e];        // {f, s, s*off, w}
                const float hi  = cst.x * tm;
                const float lo  = fmaf(cst.x, tm, -hi);  // exact residual
                const float rev = (hi - floorf(hi)) + lo + sig;
                const float cA  = __builtin_amdgcn_cosf(rev);
                const float sA  = __builtin_amdgcn_sinf(rev);
                const float a   = fmaf(cst.y, tnm, cst.z);
                const float wb  = __builtin_amdgcn_rsqf(fmaf(a, a, 1.0f)) * cst.w;
                union { _Float16 h[2]; unsigned u; } pk;
                pk.h[0] = (_Float16)(wb * cA);
                pk.h[1] = (_Float16)(wb * sA);
                pk2[e] = pk.u;
            }
            vrow[i] = make_uint2(pk2[0], pk2[1]);        // osc 2i, 2i+1
        }
    }
    __syncthreads();

    const int q = c >> 4, cp = c & 15;
    const int cc = tid >> 3;                 // owner chunk (phase 3)
    const int j0 = (tid & 7) * 2;            // owner sample pair within half
    const float tmc = t[base + cc * 32 + 15];

#pragma unroll 1
    for (int h = 0; h < 2; ++h) {
        // ---------------- phase 2: MFMA (j-half h) ----------------
        {
            const _Float16* vh = reinterpret_cast<const _Float16*>(vlds);
#pragma unroll
            for (int n = 0; n < 3; ++n) {
                const int tile = p + 8 * n;          // 0..23
                const int tr = tile & 3, tc = tile >> 2;
                const int kbase = (tc < 2) ? 0 : 128;
                const _Float16* ap = vh + (16 * tr + cp) * 264 + kbase + q * 8;
                const _Float16* mp = Mfrag + (h * 6 + tc) * 2048 + c * 8;
                v4f acc = {0.0f, 0.0f, 0.0f, 0.0f};
#pragma unroll
                for (int kk = 0; kk < 4; ++kk) {
                    const v8h a = *reinterpret_cast<const v8h*>(ap + kk * 32);
                    const v8h b = *reinterpret_cast<const v8h*>(mp + kk * 512);
                    acc = MFMA_F16(a, b, acc);
                }
#pragma unroll
                for (int i = 0; i < 4; ++i)
                    clds[(16 * tr + 4 * q + i) * 98 + 16 * tc + cp] = acc[i];
            }
        }
        __syncthreads();

        // ---------------- phase 3: epilogue (j-half h) ----------------
        {
            const int sj = 16 * h + j0;              // sample within chunk
            const float2 tt =
                *reinterpret_cast<const float2*>(t + base + cc * 32 + sj);
            const float* Cr = clds + cc * 98 + j0;

            float o2[2];
#pragma unroll
            for (int e = 0; e < 2; ++e) {
                const float tje = e ? tt.y : tt.x;
                // 2*pi*(t_j - (tm + (j-15)*dt)): f32 rounding jitter, rad/Hz
                const float d2p =
                    TWO_PI_F * fmaf(-(float)(sj + e - 15), dtf, tje - tmc);
                const float Cm  = Cr[e],      Sfm = Cr[16 + e];
                const float S   = Cr[32 + e], Cc  = Cr[48 + e];
                const float Sf  = Cr[64 + e], Cf  = Cr[80 + e];

                const float m    = fmaf(-d2p, Sfm, Cm);      // modulator value
                const float mrev = m * INV2PI_F;
                const float cm = __builtin_amdgcn_cosf(mrev);
                const float sm = __builtin_amdgcn_sinf(mrev);

                const float u = fmaf(cm, S, sm * Cc);
                const float v = fmaf(cm, Cf, -(sm * Sf));
                o2[e] = fmaf(d2p, v, u);
            }
            *reinterpret_cast<float2*>(out + base + cc * 32 + sj) =
                make_float2(o2[0], o2[1]);
        }
        if (h == 0) __syncthreads();   // clds reused by ph2(h=1)
    }
}

// ---------------------------------------------------------------------------
extern "C" void kernel_launch(void* const* d_in, const int* in_sizes, int n_in,
                              void* d_out, int out_size, void* d_ws, size_t ws_size,
                              hipStream_t stream) {
    // setup_inputs() order:
    // 0:t 1:carrier_fq 2:carrier_weight 3:mod_fq 4:mod_weight 5:phase_offset
    // 6:carrier_env_slope 7:carrier_env_offset 8:mod_env_slope 9:mod_env_offset
    const float* t   = (const float*)d_in[0];
    const float* cfq = (const float*)d_in[1];
    const float* cw  = (const float*)d_in[2];
    const float* mfq = (const float*)d_in[3];
    const float* mw  = (const float*)d_in[4];
    const float* po  = (const float*)d_in[5];
    const float* ces = (const float*)d_in[6];
    const float* ceo = (const float*)d_in[7];
    const float* mes = (const float*)d_in[8];
    const float* meo = (const float*)d_in[9];
    const int T = in_sizes[0];

    float4*    banksF4 = (float4*)d_ws;
    float*     scalars = (float*)((char*)d_ws + 2048);
    _Float16*  Mfrag   = (_Float16*)((char*)d_ws + 4096);

    // fused prep (block 0: constants; blocks 1-12: M table)
    prep_kernel<<<13, 256, 0, stream>>>(t, T, cfq, cw, mfq, mw, po,
                                        ces, ceo, mes, meo,
                                        banksF4, scalars, Mfrag);

    const int grid = T / 2048;                 // 512 blocks for T = 1<<20
    fm_main_kernel<<<grid, 512, 0, stream>>>(t, banksF4, scalars, Mfrag,
                                             (float*)d_out);
}

// Round 14
// 16.562 us; speedup vs baseline: 2.0901x; 1.0636x over previous
//
#include <hip/hip_runtime.h>
#include <math.h>

#define KOSC 64
#define CHUNK 32
#define TWO_PI_F  6.28318530717958647692f
#define INV2PI_F  0.15915494309189533577f
#define MIN_SLOPE -2.0f
#define MAX_SLOPE  8.0f

typedef _Float16 v8h __attribute__((ext_vector_type(8)));
typedef float    v4f __attribute__((ext_vector_type(4)));

// gfx950 intrinsic (K=32, A/B = 8 x f16, C/D = 4 x f32).
#define MFMA_F16(a, b, c) \
    __builtin_amdgcn_mfma_f32_16x16x32_f16((a), (b), (c), 0, 0, 0)

// ---------------------------------------------------------------------------
// ws layout:
//   [0,    2048): banksF4[128] float4 {f, s, s*off, w}  (0-63 mod, 64-127 car)
//   [2048, 2064): scalars {sig(rev), 1/tmax, dt}
//   [4096, 53248): Mfrag [12 tcg][4 kk][64 lane][8] _Float16 (B-fragment order)
// ---------------------------------------------------------------------------

__device__ __forceinline__ float wave_reduce_max(float v) {
#pragma unroll
    for (int off = 32; off > 0; off >>= 1)
        v = fmaxf(v, __shfl_xor(v, off, 64));
    return v;
}
__device__ __forceinline__ float wave_reduce_sum(float v) {
#pragma unroll
    for (int off = 32; off > 0; off >>= 1)
        v += __shfl_xor(v, off, 64);
    return v;
}

// ---------------------------------------------------------------------------
// ONE fused prep kernel (13 blocks x 256) — unchanged from round 13:
//  block 0, threads 0-127 (2 waves): per-oscillator constants + scalars.
//  blocks 1-12: trig matrix M for column-tile-group tcg = blockIdx.x-1
//    (h = tcg/6 selects the j-half, tc = tcg%6 the quantity tile), RAW input
//    frequencies, hw f32 trig in REVOLUTIONS (|ang| <= 0.34 rev).
//
// M layout (B-fragment order for mfma_f32_16x16x32_f16; lane l holds
// col = l&15, k = kap0 + 8*(l>>4) + i):
//   Mfrag[tcg][kk][l][i],  kap0 = (tc<2 ? 0 : 128) + 32*kk
//   kappa = 2k -> multiplies wb*cos(A_k); 2k+1 -> wb*sin(A_k)
//   j within half: jm = (l&15) - 15 + 16*h   (chunk midpoint at j=15)
// Quantity tiles (per half):
//   tc0: Cm = cos-sum     tc1: Sfm = f*sin-sum     (modulator)
//   tc2: S  = sin-sum     tc3: C  = cos-sum
//   tc4: Sf = f*sin-sum   tc5: Cf = f*cos-sum      (carrier)
// ---------------------------------------------------------------------------
__global__ void prep_kernel(
    const float* __restrict__ t, int T,
    const float* __restrict__ cfq, const float* __restrict__ cwt,
    const float* __restrict__ mfq, const float* __restrict__ mwt,
    const float* __restrict__ po,
    const float* __restrict__ ces, const float* __restrict__ ceo,
    const float* __restrict__ mes, const float* __restrict__ meo,
    float4* __restrict__ banksF4, float* __restrict__ scalars,
    _Float16* __restrict__ Mfrag)
{
    if (blockIdx.x == 0) {
        const int k = threadIdx.x;
        if (k >= 128) return;
        const int bank = k >> 6;
        const int idx  = k & 63;

        const float fq = bank ? cfq[idx] : mfq[idx];
        const float wt = bank ? cwt[idx] : mwt[idx];
        const float sl = bank ? ces[idx] : mes[idx];
        const float of = bank ? ceo[idx] : meo[idx];

        const float mx = wave_reduce_max(wt);
        const float ex = expf(wt - mx);
        const float sm = wave_reduce_sum(ex);
        const float w  = ex / sm;

        const float sg   = 1.0f / (1.0f + expf(-sl));
        const float s    = exp2f(sg * (MAX_SLOPE - MIN_SLOPE) + MIN_SLOPE);
        const float offv = tanhf(of) * 0.5f;

        banksF4[bank * 64 + idx] = make_float4(fq, s, s * offv, w);

        if (k == 0) {
            scalars[0] = 1.0f / (1.0f + expf(-po[0]));  // phase offset, rev
            scalars[1] = 1.0f / t[T - 1];
            scalars[2] = t[1] - t[0];
        }
        return;
    }

    // ----- M-table blocks -----
    const int tcg = blockIdx.x - 1;                // 0..11
    const int h   = tcg / 6;
    const int tc  = tcg % 6;
    const int kk  = threadIdx.x >> 6;              // 0..3
    const int l   = threadIdx.x & 63;
    const int q   = l >> 4, cp = l & 15;
    const float jm  = (float)(cp - 15 + 16 * h);   // j - 15, j in this half
    const float dt  = t[1] - t[0];
    const int kap0 = ((tc < 2) ? 0 : 128) + 32 * kk;

#pragma unroll
    for (int i = 0; i < 8; ++i) {
        const int kap  = kap0 + q * 8 + i;
        const int bank = kap >> 7;
        const int kidx = (kap & 127) >> 1;
        const int part = kap & 1;
        const float f  = bank ? cfq[kidx] : mfq[kidx];   // raw input freq

        const float ang = jm * (f * dt);           // revolutions, |ang|<=0.34
        const float cj = __builtin_amdgcn_cosf(ang);
        const float sj = __builtin_amdgcn_sinf(ang);

        float val = 0.0f;
        if (bank == 0) {
            if      (tc == 0) val = part ? -sj : cj;        // Cm
            else if (tc == 1) val = (part ? cj : sj) * f;   // Sfm
        } else {
            if      (tc == 2) val = part ? cj : sj;         // S
            else if (tc == 3) val = part ? -sj : cj;        // C
            else if (tc == 4) val = (part ? cj : sj) * f;   // Sf
            else if (tc == 5) val = (part ? -sj : cj) * f;  // Cf
        }
        Mfrag[(((tcg * 4 + kk) * 64 + l) << 3) + i] = (_Float16)val;
    }
}

// ---------------------------------------------------------------------------
// Main kernel: block = 512 threads = 8 waves; 64 chunks x 32 samples = 2048
// samples per block; grid = 512 = 2 blocks/CU.
// Phase 1: wave p computes phasors for its 16 oscillators (wave-uniform
//   consts -> s_load) at each lane's chunk midpoint tm = t[chunk*32+15]
//   (exact Dekker + Sterbenz frac + hw trig in revolutions), packed fp16
//   (wb*cosA, wb*sinA) -> vlds.  ONE barrier.
// Phase 2+3 (fused, in-register, no further barriers): wave p owns
//   (tr = p&3, h = p>>2). It computes ALL 6 quantity tiles for that
//   (chunk-tile, j-half): 8 x ds_read_b128 A-fragments (shared across tc),
//   24 MFMA. The D-fragment mapping [m89] puts all 6 quantities for cell
//   (chunk 16tr+4q+i, sample cp+16h) in the SAME lane, reg i -> epilogue
//   (jitter-corrected mod -> one trig pair -> FM rotation) entirely in
//   registers; scalar stores coalesce in 16-lane segments.
// ---------------------------------------------------------------------------
__global__ void __launch_bounds__(512, 4) fm_main_kernel(
    const float* __restrict__ t,
    const float4* __restrict__ banksF4,
    const float* __restrict__ scalars,
    const _Float16* __restrict__ Mfrag,
    float* __restrict__ out)
{
    // V rows padded to 132 words (264 halves, 528 B): 16B-aligned half8 loads.
    __shared__ unsigned vlds[64 * 132];   // 33792 B

    const int tid  = threadIdx.x;
    const int c    = tid & 63;                                  // lane / chunk
    const int p    = __builtin_amdgcn_readfirstlane(tid >> 6);  // wave 0..7
    const int base = blockIdx.x * 2048;

    const float sig     = scalars[0];
    const float invtmax = scalars[1];
    const float dtf     = scalars[2];

    // ---------------- phase 1: phasors ----------------
    {
        const float tm  = t[base + c * 32 + 15];
        const float tnm = fmaf(tm, invtmax, -0.5f);
        const float4* bb = banksF4 + p * 16;     // wave-uniform -> s_load
        uint2* vrow = reinterpret_cast<uint2*>(vlds + c * 132 + p * 16);
#pragma unroll
        for (int i = 0; i < 8; ++i) {
            unsigned pk2[2];
#pragma unroll
            for (int e = 0; e < 2; ++e) {
                const float4 cst = bb[2 * i + e];        // {f, s, s*off, w}
                const float hi  = cst.x * tm;
                const float lo  = fmaf(cst.x, tm, -hi);  // exact residual
                const float rev = (hi - floorf(hi)) + lo + sig;
                const float cA  = __builtin_amdgcn_cosf(rev);
                const float sA  = __builtin_amdgcn_sinf(rev);
                const float a   = fmaf(cst.y, tnm, cst.z);
                const float wb  = __builtin_amdgcn_rsqf(fmaf(a, a, 1.0f)) * cst.w;
                union { _Float16 h[2]; unsigned u; } pk;
                pk.h[0] = (_Float16)(wb * cA);
                pk.h[1] = (_Float16)(wb * sA);
                pk2[e] = pk.u;
            }
            vrow[i] = make_uint2(pk2[0], pk2[1]);        // osc 2i, 2i+1
        }
    }
    __syncthreads();

    // ---------------- phase 2+3: MFMA + in-register epilogue ----------------
    const int tr = p & 3;                    // chunk-tile
    const int h  = p >> 2;                   // j-half
    const int q  = c >> 4, cp = c & 15;

    const _Float16* vh = reinterpret_cast<const _Float16*>(vlds);

    // A fragments (row = 16*tr + cp, k = kbase + 32*kk + 8*q + i), shared
    // across all 6 quantity tiles of this wave.
    v8h Amod[4], Acar[4];
    {
        const _Float16* ap = vh + (16 * tr + cp) * 264 + q * 8;
#pragma unroll
        for (int kk = 0; kk < 4; ++kk) {
            Amod[kk] = *reinterpret_cast<const v8h*>(ap + kk * 32);
            Acar[kk] = *reinterpret_cast<const v8h*>(ap + 128 + kk * 32);
        }
    }

    v4f acc[6];
#pragma unroll
    for (int tc = 0; tc < 6; ++tc) {
        const _Float16* mp = Mfrag + (h * 6 + tc) * 2048 + c * 8;
        v4f a = {0.0f, 0.0f, 0.0f, 0.0f};
#pragma unroll
        for (int kk = 0; kk < 4; ++kk) {
            const v8h b = *reinterpret_cast<const v8h*>(mp + kk * 512);
            a = MFMA_F16((tc < 2) ? Amod[kk] : Acar[kk], b, a);
        }
        acc[tc] = a;
    }

    // epilogue: lane owns cells (chunk = 16*tr + 4*q + i, sample = cp + 16*h)
    const int sj = cp + 16 * h;
#pragma unroll
    for (int i = 0; i < 4; ++i) {
        const int ch  = 16 * tr + 4 * q + i;
        const int off = base + ch * 32;
        const float tmc = t[off + 15];
        const float tje = t[off + sj];
        // 2*pi*(t_j - (tm + (j-15)*dt)): f32 rounding jitter, rad per Hz
        const float d2p = TWO_PI_F * fmaf(-(float)(sj - 15), dtf, tje - tmc);

        const float Cm  = acc[0][i], Sfm = acc[1][i];
        const float S   = acc[2][i], Cc  = acc[3][i];
        const float Sf  = acc[4][i], Cf  = acc[5][i];

        const float m    = fmaf(-d2p, Sfm, Cm);          // modulator value
        const float mrev = m * INV2PI_F;
        const float cm = __builtin_amdgcn_cosf(mrev);
        const float sm = __builtin_amdgcn_sinf(mrev);

        const float u = fmaf(cm, S, sm * Cc);
        const float v = fmaf(cm, Cf, -(sm * Sf));
        out[off + sj] = fmaf(d2p, v, u);
    }
}

// ---------------------------------------------------------------------------
extern "C" void kernel_launch(void* const* d_in, const int* in_sizes, int n_in,
                              void* d_out, int out_size, void* d_ws, size_t ws_size,
                              hipStream_t stream) {
    // setup_inputs() order:
    // 0:t 1:carrier_fq 2:carrier_weight 3:mod_fq 4:mod_weight 5:phase_offset
    // 6:carrier_env_slope 7:carrier_env_offset 8:mod_env_slope 9:mod_env_offset
    const float* t   = (const float*)d_in[0];
    const float* cfq = (const float*)d_in[1];
    const float* cw  = (const float*)d_in[2];
    const float* mfq = (const float*)d_in[3];
    const float* mw  = (const float*)d_in[4];
    const float* po  = (const float*)d_in[5];
    const float* ces = (const float*)d_in[6];
    const float* ceo = (const float*)d_in[7];
    const float* mes = (const float*)d_in[8];
    const float* meo = (const float*)d_in[9];
    const int T = in_sizes[0];

    float4*    banksF4 = (float4*)d_ws;
    float*     scalars = (float*)((char*)d_ws + 2048);
    _Float16*  Mfrag   = (_Float16*)((char*)d_ws + 4096);

    // fused prep (block 0: constants; blocks 1-12: M table)
    prep_kernel<<<13, 256, 0, stream>>>(t, T, cfq, cw, mfq, mw, po,
                                        ces, ceo, mes, meo,
                                        banksF4, scalars, Mfrag);

    const int grid = T / 2048;                 // 512 blocks for T = 1<<20
    fm_main_kernel<<<grid, 512, 0, stream>>>(t, banksF4, scalars, Mfrag,
                                             (float*)d_out);
}